// Round 2
// baseline (991.989 us; speedup 1.0000x reference)
//
#include <hip/hip_runtime.h>
#include <hip/hip_bf16.h>
#include <stdint.h>

typedef short short8 __attribute__((ext_vector_type(8)));
typedef float f32x4 __attribute__((ext_vector_type(4)));

#define M_Q   25088   // B*H*W = 512*49
#define M_S   3136    // NS*HS*WS = 16*196
#define IN_   12544
#define SHIFTC 40.0f
#define NZ    4       // attention key-split
#define FZ    8       // fc6 K-split

__device__ __forceinline__ ushort f2bf(float f) {
  union { float f; uint32_t u; } v; v.f = f;
  uint32_t r = v.u + 0x7fffu + ((v.u >> 16) & 1u);
  return (ushort)(r >> 16);
}
__device__ __forceinline__ float bf2f(ushort u) {
  union { uint32_t u; float f; } v; v.u = ((uint32_t)u) << 16;
  return v.f;
}
__device__ __forceinline__ f32x4 mfma16(short8 a, short8 b, f32x4 c) {
  return __builtin_amdgcn_mfma_f32_16x16x32_bf16(a, b, c, 0, 0, 0);
}

// ---------------- coalesced transpose+pack: [B][256][P] f32 -> [B*P][256] hi/lo bf16
// block: 256 thr = 4 waves; lanes = p (49 per tile); wave+ch = channel octet.
__global__ __launch_bounds__(256) void transpose_pack(
    const float* __restrict__ src, ushort* __restrict__ hi,
    ushort* __restrict__ lo, int P) {
  const int b = blockIdx.x;
  const int p0 = blockIdx.y * 49;
  const int w = threadIdx.x >> 6, l = threadIdx.x & 63;
  if (l >= 49) return;
  const int p = p0 + l;
  const float* sb = src + (size_t)b * 256 * P + p;
  const size_t orow = ((size_t)b * P + p) * 256;
#pragma unroll
  for (int ch = 0; ch < 8; ++ch) {
    const int c0 = (ch * 4 + w) * 8;
    short8 h8, l8;
#pragma unroll
    for (int j = 0; j < 8; ++j) {
      float v = sb[(size_t)(c0 + j) * P];
      ushort h = f2bf(v);
      h8[j] = (short)h;
      l8[j] = (short)f2bf(v - bf2f(h));
    }
    *(short8*)(hi + orow + c0) = h8;
    *(short8*)(lo + orow + c0) = l8;
  }
}

// stack conv weights [128,256]+[128,256] -> [256,256] hi/lo, plus biases
__global__ void pack_w(const float* __restrict__ Wqv, const float* __restrict__ Wqk,
                       const float* __restrict__ bqv, const float* __restrict__ bqk,
                       const float* __restrict__ Wsv, const float* __restrict__ Wsk,
                       const float* __restrict__ bsv, const float* __restrict__ bsk,
                       ushort* __restrict__ Wq_h, ushort* __restrict__ Wq_l, float* __restrict__ biasq,
                       ushort* __restrict__ Ws_h, ushort* __restrict__ Ws_l, float* __restrict__ biass) {
  int idx = blockIdx.x * 256 + threadIdx.x;
  if (idx < 65536) {
    int n = idx >> 8;
    const float* W = (n < 128) ? (Wqv + n * 256) : (Wqk + (n - 128) * 256);
    float v = W[idx & 255];
    ushort h = f2bf(v);
    Wq_h[idx] = h; Wq_l[idx] = f2bf(v - bf2f(h));
  } else if (idx < 131072) {
    int j = idx - 65536;
    int n = j >> 8;
    const float* W = (n < 128) ? (Wsv + n * 256) : (Wsk + (n - 128) * 256);
    float v = W[j & 255];
    ushort h = f2bf(v);
    Ws_h[j] = h; Ws_l[j] = f2bf(v - bf2f(h));
  } else if (idx < 131328) {
    int n = idx - 131072;
    biasq[n] = (n < 128) ? bqv[n] : bqk[n - 128];
  } else if (idx < 131584) {
    int n = idx - 131328;
    biass[n] = (n < 128) ? bsv[n] : bsk[n - 128];
  }
}

// ---------------- conv GEMM (split-bf16, 3-term) + fused repack epilogues -------
// Q variant: n<128 -> fuse qv half (scattered c*49+p); n>=128 -> qk hi/lo rows
__global__ __launch_bounds__(256) void gemm_conv_q(
    const ushort* __restrict__ Ah, const ushort* __restrict__ Al,
    const ushort* __restrict__ Bh, const ushort* __restrict__ Bl,
    const float* __restrict__ bias, ushort* __restrict__ fuse,
    ushort* __restrict__ qk_h, ushort* __restrict__ qk_l) {
  const int lane = threadIdx.x & 63, wv = threadIdx.x >> 6;
  const int r = lane & 15, g = lane >> 4;
  const int row0 = blockIdx.x * 64 + wv * 16;
  const ushort* arh = Ah + (size_t)(row0 + r) * 256 + g * 8;
  const ushort* arl = Al + (size_t)(row0 + r) * 256 + g * 8;
  f32x4 acc[16];
#pragma unroll
  for (int i = 0; i < 16; ++i) acc[i] = f32x4{0.f, 0.f, 0.f, 0.f};
#pragma unroll
  for (int kc = 0; kc < 8; ++kc) {
    short8 ah = *(const short8*)(arh + kc * 32);
    short8 al = *(const short8*)(arl + kc * 32);
    const ushort* bbh = Bh + r * 256 + kc * 32 + g * 8;
    const ushort* bbl = Bl + r * 256 + kc * 32 + g * 8;
#pragma unroll
    for (int nt = 0; nt < 16; ++nt) {
      short8 bh = *(const short8*)(bbh + nt * 16 * 256);
      short8 bl = *(const short8*)(bbl + nt * 16 * 256);
      acc[nt] = mfma16(ah, bh, acc[nt]);
      acc[nt] = mfma16(al, bh, acc[nt]);
      acc[nt] = mfma16(ah, bl, acc[nt]);
    }
  }
  const int qr = row0 + g * 4;
#pragma unroll
  for (int nt = 0; nt < 16; ++nt) {
    int n = nt * 16 + r;
    float bs = bias[n];
#pragma unroll
    for (int e = 0; e < 4; ++e) {
      float v = acc[nt][e] + bs;
      int q = qr + e;
      if (n < 128) {
        int b = q / 49, p = q - b * 49;
        fuse[(size_t)b * IN_ + n * 49 + p] = f2bf(v);
      } else {
        size_t j = (size_t)q * 128 + (n - 128);
        ushort h = f2bf(v);
        qk_h[j] = h; qk_l[j] = f2bf(v - bf2f(h));
      }
    }
  }
}

// S variant: n<128 -> svT [128][3136]; n>=128 -> sk hi/lo rows
__global__ __launch_bounds__(256) void gemm_conv_s(
    const ushort* __restrict__ Ah, const ushort* __restrict__ Al,
    const ushort* __restrict__ Bh, const ushort* __restrict__ Bl,
    const float* __restrict__ bias, ushort* __restrict__ svT,
    ushort* __restrict__ sk_h, ushort* __restrict__ sk_l) {
  const int lane = threadIdx.x & 63, wv = threadIdx.x >> 6;
  const int r = lane & 15, g = lane >> 4;
  const int row0 = blockIdx.x * 64 + wv * 16;
  const ushort* arh = Ah + (size_t)(row0 + r) * 256 + g * 8;
  const ushort* arl = Al + (size_t)(row0 + r) * 256 + g * 8;
  f32x4 acc[16];
#pragma unroll
  for (int i = 0; i < 16; ++i) acc[i] = f32x4{0.f, 0.f, 0.f, 0.f};
#pragma unroll
  for (int kc = 0; kc < 8; ++kc) {
    short8 ah = *(const short8*)(arh + kc * 32);
    short8 al = *(const short8*)(arl + kc * 32);
    const ushort* bbh = Bh + r * 256 + kc * 32 + g * 8;
    const ushort* bbl = Bl + r * 256 + kc * 32 + g * 8;
#pragma unroll
    for (int nt = 0; nt < 16; ++nt) {
      short8 bh = *(const short8*)(bbh + nt * 16 * 256);
      short8 bl = *(const short8*)(bbl + nt * 16 * 256);
      acc[nt] = mfma16(ah, bh, acc[nt]);
      acc[nt] = mfma16(al, bh, acc[nt]);
      acc[nt] = mfma16(ah, bl, acc[nt]);
    }
  }
  const int qr = row0 + g * 4;
#pragma unroll
  for (int nt = 0; nt < 16; ++nt) {
    int n = nt * 16 + r;
    float bs = bias[n];
#pragma unroll
    for (int e = 0; e < 4; ++e) {
      float v = acc[nt][e] + bs;
      int k = qr + e;
      if (n < 128) {
        svT[(size_t)n * M_S + k] = f2bf(v);
      } else {
        size_t j = (size_t)k * 128 + (n - 128);
        ushort h = f2bf(v);
        sk_h[j] = h; sk_l[j] = f2bf(v - bf2f(h));
      }
    }
  }
}

// ---------------- fused attention, key-split NZ=4 ----------------
// 1 wave per 32 q-rows x 1 key-chunk; writes partial (num, den).
// 98 key-tiles split 25/25/24/24.
__global__ __launch_bounds__(64, 4) void attn_kernel(
    const ushort* __restrict__ Qh, const ushort* __restrict__ Ql,
    const ushort* __restrict__ Kh, const ushort* __restrict__ Kl,
    const ushort* __restrict__ Vt, float* __restrict__ pnum,
    float* __restrict__ pden) {
  __shared__ ushort plds[2][16][32];
  const int lane = threadIdx.x;
  const int r = lane & 15, g = lane >> 4;
  const int q0 = blockIdx.x * 32;
  const int z = blockIdx.y;
  const int t0 = z * 24 + (z < 2 ? z : 2);
  const int tn = 24 + (z < 2 ? 1 : 0);

  short8 aqh[2][4], aql[2][4];
#pragma unroll
  for (int mt = 0; mt < 2; ++mt)
#pragma unroll
    for (int kc = 0; kc < 4; ++kc) {
      const int rowq = q0 + mt * 16 + r;
      aqh[mt][kc] = *(const short8*)(Qh + (size_t)rowq * 128 + kc * 32 + g * 8);
      aql[mt][kc] = *(const short8*)(Ql + (size_t)rowq * 128 + kc * 32 + g * 8);
    }

  f32x4 acc[2][8];
#pragma unroll
  for (int mt = 0; mt < 2; ++mt)
#pragma unroll
    for (int ct = 0; ct < 8; ++ct) acc[mt][ct] = f32x4{0.f, 0.f, 0.f, 0.f};
  float den[2][4];
#pragma unroll
  for (int mt = 0; mt < 2; ++mt)
#pragma unroll
    for (int e = 0; e < 4; ++e) den[mt][e] = 0.f;

  for (int t = t0; t < t0 + tn; ++t) {
    const int kb = t * 32;
    f32x4 lg[2][2];
#pragma unroll
    for (int kt = 0; kt < 2; ++kt) {
      const int krow = kb + kt * 16 + r;
      short8 bh[4], bl[4];
#pragma unroll
      for (int kc = 0; kc < 4; ++kc) {
        bh[kc] = *(const short8*)(Kh + (size_t)krow * 128 + kc * 32 + g * 8);
        bl[kc] = *(const short8*)(Kl + (size_t)krow * 128 + kc * 32 + g * 8);
      }
#pragma unroll
      for (int mt = 0; mt < 2; ++mt) {
        f32x4 c = f32x4{0.f, 0.f, 0.f, 0.f};
#pragma unroll
        for (int kc = 0; kc < 4; ++kc) {
          c = mfma16(aqh[mt][kc], bh[kc], c);
          c = mfma16(aql[mt][kc], bh[kc], c);
          c = mfma16(aqh[mt][kc], bl[kc], c);
        }
        lg[mt][kt] = c;
      }
    }
#pragma unroll
    for (int mt = 0; mt < 2; ++mt)
#pragma unroll
      for (int kt = 0; kt < 2; ++kt)
#pragma unroll
        for (int e = 0; e < 4; ++e) {
          float p = __expf(lg[mt][kt][e] - SHIFTC);
          den[mt][e] += p;
          plds[mt][g * 4 + e][kt * 16 + r] = f2bf(p);
        }
    __syncthreads();
#pragma unroll
    for (int mt = 0; mt < 2; ++mt) {
      short8 pf = *(const short8*)(&plds[mt][r][g * 8]);
#pragma unroll
      for (int ct = 0; ct < 8; ++ct) {
        short8 vf = *(const short8*)(Vt + (size_t)(ct * 16 + r) * M_S + kb + g * 8);
        acc[mt][ct] = mfma16(pf, vf, acc[mt][ct]);
      }
    }
    __syncthreads();
  }

  // reduce den across r lanes (keys live on lane bits 0-3)
#pragma unroll
  for (int mt = 0; mt < 2; ++mt)
#pragma unroll
    for (int e = 0; e < 4; ++e) {
      float d = den[mt][e];
      d += __shfl_xor(d, 1);
      d += __shfl_xor(d, 2);
      d += __shfl_xor(d, 4);
      d += __shfl_xor(d, 8);
      den[mt][e] = d;
    }
#pragma unroll
  for (int mt = 0; mt < 2; ++mt)
#pragma unroll
    for (int ct = 0; ct < 8; ++ct)
#pragma unroll
      for (int e = 0; e < 4; ++e) {
        int q = q0 + mt * 16 + g * 4 + e;
        int c = ct * 16 + r;
        pnum[((size_t)z * M_Q + q) * 128 + c] = acc[mt][ct][e];
      }
  if (r == 0) {
#pragma unroll
    for (int mt = 0; mt < 2; ++mt)
#pragma unroll
      for (int e = 0; e < 4; ++e)
        pden[(size_t)z * M_Q + q0 + mt * 16 + g * 4 + e] = den[mt][e];
  }
}

// combine key-split partials -> att half of fuse
__global__ void attn_reduce(const float* __restrict__ pnum, const float* __restrict__ pden,
                            ushort* __restrict__ fuse) {
  int idx = blockIdx.x * 256 + threadIdx.x;  // exactly 25088*32 (c-quads)
  int q = idx >> 5;
  int c4 = (idx & 31) * 4;
  float4 s = {0.f, 0.f, 0.f, 0.f};
  float d = 0.f;
#pragma unroll
  for (int z = 0; z < NZ; ++z) {
    float4 v = *(const float4*)(pnum + ((size_t)z * M_Q + q) * 128 + c4);
    s.x += v.x; s.y += v.y; s.z += v.z; s.w += v.w;
    d += pden[(size_t)z * M_Q + q];
  }
  float inv = 1.0f / d;
  int b = q / 49, p = q - b * 49;
  size_t base = (size_t)b * IN_ + 6272 + p;
  fuse[base + (size_t)(c4 + 0) * 49] = f2bf(s.x * inv);
  fuse[base + (size_t)(c4 + 1) * 49] = f2bf(s.y * inv);
  fuse[base + (size_t)(c4 + 2) * 49] = f2bf(s.z * inv);
  fuse[base + (size_t)(c4 + 3) * 49] = f2bf(s.w * inv);
}

// ---------------- fc6: [512][12544] x [2048][12544]^T, K-split FZ=8 ----------------
// block covers all 512 m-rows (4 waves x 128) x 64 n-cols; W6 read exactly once.
__global__ __launch_bounds__(256) void fc6_kernel(
    const ushort* __restrict__ fuse, const float* __restrict__ W6c,
    const float* __restrict__ W6r, float* __restrict__ part) {
  const int lane = threadIdx.x & 63, wv = threadIdx.x >> 6;
  const int r = lane & 15, g = lane >> 4;
  const int m0 = wv * 128;
  const int n0 = blockIdx.x * 64;
  const int kz = blockIdx.y;
  const int k0 = kz * 1568;
  f32x4 acc[8][4];
#pragma unroll
  for (int mt = 0; mt < 8; ++mt)
#pragma unroll
    for (int nt = 0; nt < 4; ++nt) acc[mt][nt] = f32x4{0.f, 0.f, 0.f, 0.f};
  const float* wrow[4];
#pragma unroll
  for (int nt = 0; nt < 4; ++nt) {
    int n = n0 + nt * 16 + r;
    wrow[nt] = (n < 1024) ? (W6c + (size_t)n * IN_) : (W6r + (size_t)(n - 1024) * IN_);
  }
  for (int kk = 0; kk < 1568; kk += 32) {
    const int kcol = k0 + kk + g * 8;
    short8 af[8];
#pragma unroll
    for (int mt = 0; mt < 8; ++mt)
      af[mt] = *(const short8*)(fuse + (size_t)(m0 + mt * 16 + r) * IN_ + kcol);
    short8 bfr[4];
#pragma unroll
    for (int nt = 0; nt < 4; ++nt) {
      const float* wp = wrow[nt] + kcol;
      float4 w0 = *(const float4*)wp;
      float4 w1 = *(const float4*)(wp + 4);
      short8 bb;
      bb[0] = (short)f2bf(w0.x); bb[1] = (short)f2bf(w0.y);
      bb[2] = (short)f2bf(w0.z); bb[3] = (short)f2bf(w0.w);
      bb[4] = (short)f2bf(w1.x); bb[5] = (short)f2bf(w1.y);
      bb[6] = (short)f2bf(w1.z); bb[7] = (short)f2bf(w1.w);
      bfr[nt] = bb;
    }
#pragma unroll
    for (int mt = 0; mt < 8; ++mt)
#pragma unroll
      for (int nt = 0; nt < 4; ++nt) acc[mt][nt] = mfma16(af[mt], bfr[nt], acc[mt][nt]);
  }
#pragma unroll
  for (int mt = 0; mt < 8; ++mt)
#pragma unroll
    for (int nt = 0; nt < 4; ++nt)
#pragma unroll
      for (int e = 0; e < 4; ++e) {
        int m = m0 + mt * 16 + g * 4 + e;
        int n = n0 + nt * 16 + r;
        part[(size_t)kz * 1048576 + (size_t)m * 2048 + n] = acc[mt][nt][e];
      }
}

// sum split-K partials + bias + relu -> X7 bf16 [512][2048]
__global__ void fc6_reduce(const float* __restrict__ part, const float* __restrict__ b6c,
                           const float* __restrict__ b6r, ushort* __restrict__ X7) {
  int idx = blockIdx.x * 256 + threadIdx.x;  // exactly 512*2048
  int n = idx & 2047;
  float s = 0.f;
#pragma unroll
  for (int z = 0; z < FZ; ++z) s += part[(size_t)z * 1048576 + idx];
  s += (n < 1024) ? b6c[n] : b6r[n - 1024];
  s = fmaxf(s, 0.f);
  X7[idx] = f2bf(s);
}

// ---------------- fc7: [512][1024] x [1024][1024]^T per half ----------------
__global__ __launch_bounds__(256) void fc7_kernel(
    const ushort* __restrict__ X7, const float* __restrict__ W7c,
    const float* __restrict__ W7r, const float* __restrict__ b7c,
    const float* __restrict__ b7r, float* __restrict__ out) {
  const int lane = threadIdx.x & 63, wv = threadIdx.x >> 6;
  const int r = lane & 15, g = lane >> 4;
  const int m0 = blockIdx.x * 64 + wv * 16;
  const int n0 = blockIdx.y * 64;
  const int half = (n0 >= 1024) ? 1 : 0;
  const int nn0 = n0 - half * 1024;
  const float* W7 = half ? W7r : W7c;
  const float* b7 = half ? b7r : b7c;
  f32x4 acc[4];
#pragma unroll
  for (int nt = 0; nt < 4; ++nt) acc[nt] = f32x4{0.f, 0.f, 0.f, 0.f};
  const ushort* arow = X7 + (size_t)(m0 + r) * 2048 + half * 1024;
  for (int kk = 0; kk < 1024; kk += 32) {
    short8 a = *(const short8*)(arow + kk + g * 8);
#pragma unroll
    for (int nt = 0; nt < 4; ++nt) {
      const float* wp = W7 + (size_t)(nn0 + nt * 16 + r) * 1024 + kk + g * 8;
      float4 w0 = *(const float4*)wp;
      float4 w1 = *(const float4*)(wp + 4);
      short8 bb;
      bb[0] = (short)f2bf(w0.x); bb[1] = (short)f2bf(w0.y);
      bb[2] = (short)f2bf(w0.z); bb[3] = (short)f2bf(w0.w);
      bb[4] = (short)f2bf(w1.x); bb[5] = (short)f2bf(w1.y);
      bb[6] = (short)f2bf(w1.z); bb[7] = (short)f2bf(w1.w);
      acc[nt] = mfma16(a, bb, acc[nt]);
    }
  }
  float* obase = out + (size_t)half * 524288;
#pragma unroll
  for (int nt = 0; nt < 4; ++nt) {
#pragma unroll
    for (int e = 0; e < 4; ++e) {
      int m = m0 + g * 4 + e;
      int n = nn0 + nt * 16 + r;
      obase[(size_t)m * 1024 + n] = fmaxf(acc[nt][e] + b7[n], 0.f);
    }
  }
}

// ---------------- launch ----------------
extern "C" void kernel_launch(void* const* d_in, const int* in_sizes, int n_in,
                              void* d_out, int out_size, void* d_ws, size_t ws_size,
                              hipStream_t stream) {
  const float* x    = (const float*)d_in[0];
  const float* sup  = (const float*)d_in[1];
  const float* Wqv  = (const float*)d_in[2];
  const float* bqv  = (const float*)d_in[3];
  const float* Wqk  = (const float*)d_in[4];
  const float* bqk  = (const float*)d_in[5];
  const float* Wsv  = (const float*)d_in[6];
  const float* bsv  = (const float*)d_in[7];
  const float* Wsk  = (const float*)d_in[8];
  const float* bsk  = (const float*)d_in[9];
  const float* W6c  = (const float*)d_in[10];
  const float* b6c  = (const float*)d_in[11];
  const float* W7c  = (const float*)d_in[12];
  const float* b7c  = (const float*)d_in[13];
  const float* W6r  = (const float*)d_in[14];
  const float* b6r  = (const float*)d_in[15];
  const float* W7r  = (const float*)d_in[16];
  const float* b7r  = (const float*)d_in[17];
  float* out = (float*)d_out;

  char* base = (char*)d_ws;
  size_t off = 0;
  auto alloc = [&](size_t bytes) {
    char* p = base + off;
    off += (bytes + 255) & ~(size_t)255;
    return p;
  };
  // Region A: time-shared. Stage 1: Xp/Xs hi/lo (28.9MB). Stage 2: attn pnum
  // (51.4MB). Stage 3: fc6 part (33.6MB). Sized for the max.
  char* regionA = alloc((size_t)NZ * M_Q * 128 * 4);          // 51,380,224 B
  ushort* Xp_h = (ushort*)(regionA);
  ushort* Xp_l = (ushort*)(regionA + 12845056);
  ushort* Xs_h = (ushort*)(regionA + 25690112);
  ushort* Xs_l = (ushort*)(regionA + 27295744);
  float*  pnum = (float*)regionA;
  float*  part = (float*)regionA;
  // Persistent region
  ushort* Wq_h = (ushort*)alloc(65536 * 2);
  ushort* Wq_l = (ushort*)alloc(65536 * 2);
  ushort* Ws_h = (ushort*)alloc(65536 * 2);
  ushort* Ws_l = (ushort*)alloc(65536 * 2);
  float*  biasq = (float*)alloc(256 * 4);
  float*  biass = (float*)alloc(256 * 4);
  ushort* fuse = (ushort*)alloc((size_t)512 * IN_ * 2);
  ushort* qk_h = (ushort*)alloc((size_t)M_Q * 128 * 2);
  ushort* qk_l = (ushort*)alloc((size_t)M_Q * 128 * 2);
  ushort* sk_h = (ushort*)alloc((size_t)M_S * 128 * 2);
  ushort* sk_l = (ushort*)alloc((size_t)M_S * 128 * 2);
  ushort* svT  = (ushort*)alloc((size_t)M_S * 128 * 2);
  float*  pden = (float*)alloc((size_t)NZ * M_Q * 4);
  ushort* X7   = (ushort*)alloc((size_t)512 * 2048 * 2);
  if (off > ws_size) return;  // insufficient scratch; validation will show poison

  // 1) coalesced transpose+pack to bf16 hi/lo, token-major
  transpose_pack<<<dim3(512, 1), dim3(256), 0, stream>>>(x, Xp_h, Xp_l, 49);
  transpose_pack<<<dim3(16, 4), dim3(256), 0, stream>>>(sup, Xs_h, Xs_l, 196);
  pack_w<<<dim3(515), dim3(256), 0, stream>>>(Wqv, Wqk, bqv, bqk, Wsv, Wsk, bsv, bsk,
                                              Wq_h, Wq_l, biasq, Ws_h, Ws_l, biass);
  // 2) 1x1 convs with fused repack epilogues
  gemm_conv_q<<<dim3(392), dim3(256), 0, stream>>>(Xp_h, Xp_l, Wq_h, Wq_l, biasq,
                                                   fuse, qk_h, qk_l);
  gemm_conv_s<<<dim3(49), dim3(256), 0, stream>>>(Xs_h, Xs_l, Ws_h, Ws_l, biass,
                                                  svT, sk_h, sk_l);
  // 3) fused attention (key-split) + combine
  attn_kernel<<<dim3(784, NZ), dim3(64), 0, stream>>>(qk_h, qk_l, sk_h, sk_l, svT,
                                                      pnum, pden);
  attn_reduce<<<dim3(3136), dim3(256), 0, stream>>>(pnum, pden, fuse);
  // 4) fc6 (K-split deterministic) + reduce+relu
  fc6_kernel<<<dim3(32, FZ), dim3(256), 0, stream>>>(fuse, W6c, W6r, part);
  fc6_reduce<<<dim3(4096), dim3(256), 0, stream>>>(part, b6c, b6r, X7);
  // 5) fc7 + bias + relu -> d_out (xc then xr)
  fc7_kernel<<<dim3(8, 32), dim3(256), 0, stream>>>(X7, W7c, W7r, b7c, b7r, out);
}

// Round 3
// 596.340 us; speedup vs baseline: 1.6635x; 1.6635x over previous
//
#include <hip/hip_runtime.h>
#include <hip/hip_bf16.h>
#include <stdint.h>

typedef short short8 __attribute__((ext_vector_type(8)));
typedef float f32x4 __attribute__((ext_vector_type(4)));

#define M_Q   25088   // B*H*W = 512*49
#define M_S   3136    // NS*HS*WS = 16*196
#define IN_   12544
#define SHIFTC 40.0f
#define NZ    4       // attention key-split
#define FZ    8       // fc6 K-split

__device__ __forceinline__ ushort f2bf(float f) {
  union { float f; uint32_t u; } v; v.f = f;
  uint32_t r = v.u + 0x7fffu + ((v.u >> 16) & 1u);
  return (ushort)(r >> 16);
}
__device__ __forceinline__ float bf2f(ushort u) {
  union { uint32_t u; float f; } v; v.u = ((uint32_t)u) << 16;
  return v.f;
}
__device__ __forceinline__ f32x4 mfma16(short8 a, short8 b, f32x4 c) {
  return __builtin_amdgcn_mfma_f32_16x16x32_bf16(a, b, c, 0, 0, 0);
}

// ---------------- coalesced transpose+pack: [B][256][P] f32 -> [B*P][256] hi/lo bf16
__global__ __launch_bounds__(256) void transpose_pack(
    const float* __restrict__ src, ushort* __restrict__ hi,
    ushort* __restrict__ lo, int P) {
  const int b = blockIdx.x;
  const int p0 = blockIdx.y * 49;
  const int w = threadIdx.x >> 6, l = threadIdx.x & 63;
  if (l >= 49) return;
  const int p = p0 + l;
  const float* sb = src + (size_t)b * 256 * P + p;
  const size_t orow = ((size_t)b * P + p) * 256;
#pragma unroll
  for (int ch = 0; ch < 8; ++ch) {
    const int c0 = (ch * 4 + w) * 8;
    short8 h8, l8;
#pragma unroll
    for (int j = 0; j < 8; ++j) {
      float v = sb[(size_t)(c0 + j) * P];
      ushort h = f2bf(v);
      h8[j] = (short)h;
      l8[j] = (short)f2bf(v - bf2f(h));
    }
    *(short8*)(hi + orow + c0) = h8;
    *(short8*)(lo + orow + c0) = l8;
  }
}

// stack conv weights [128,256]+[128,256] -> [256,256] hi/lo, plus biases
__global__ void pack_w(const float* __restrict__ Wqv, const float* __restrict__ Wqk,
                       const float* __restrict__ bqv, const float* __restrict__ bqk,
                       const float* __restrict__ Wsv, const float* __restrict__ Wsk,
                       const float* __restrict__ bsv, const float* __restrict__ bsk,
                       ushort* __restrict__ Wq_h, ushort* __restrict__ Wq_l, float* __restrict__ biasq,
                       ushort* __restrict__ Ws_h, ushort* __restrict__ Ws_l, float* __restrict__ biass) {
  int idx = blockIdx.x * 256 + threadIdx.x;
  if (idx < 65536) {
    int n = idx >> 8;
    const float* W = (n < 128) ? (Wqv + n * 256) : (Wqk + (n - 128) * 256);
    float v = W[idx & 255];
    ushort h = f2bf(v);
    Wq_h[idx] = h; Wq_l[idx] = f2bf(v - bf2f(h));
  } else if (idx < 131072) {
    int j = idx - 65536;
    int n = j >> 8;
    const float* W = (n < 128) ? (Wsv + n * 256) : (Wsk + (n - 128) * 256);
    float v = W[j & 255];
    ushort h = f2bf(v);
    Ws_h[j] = h; Ws_l[j] = f2bf(v - bf2f(h));
  } else if (idx < 131328) {
    int n = idx - 131072;
    biasq[n] = (n < 128) ? bqv[n] : bqk[n - 128];
  } else if (idx < 131584) {
    int n = idx - 131328;
    biass[n] = (n < 128) ? bsv[n] : bsk[n - 128];
  }
}

// W6 [n][c*49+p] f32 -> W6p [n][p*256+c] bf16 (one block per n, coalesced reads)
__global__ __launch_bounds__(256) void pack_w6(
    const float* __restrict__ W6c, const float* __restrict__ W6r,
    ushort* __restrict__ W6p) {
  const int n = blockIdx.x;
  const float* src = (n < 1024) ? (W6c + (size_t)n * IN_)
                                : (W6r + (size_t)(n - 1024) * IN_);
  ushort* dst = W6p + (size_t)n * IN_;
  for (int j = 0; j < 49; ++j) {
    int i = j * 256 + threadIdx.x;        // coalesced read index
    float v = src[i];
    int c = i / 49;
    int p = i - c * 49;
    dst[p * 256 + c] = f2bf(v);
  }
}

// W7 -> bf16 [2048][1024] (xc rows then xr rows)
__global__ void pack_w7(const float* __restrict__ W7c, const float* __restrict__ W7r,
                        ushort* __restrict__ W7p) {
  int idx = blockIdx.x * 256 + threadIdx.x;  // exactly 2048*1024
  float v = (idx < 1048576) ? W7c[idx] : W7r[idx - 1048576];
  W7p[idx] = f2bf(v);
}

// ---------------- conv GEMM (split-bf16, 3-term) + fused repack epilogues -------
// Q variant: n<128 -> fuse qv half (token-major [b][p][c]); n>=128 -> qk hi/lo rows
__global__ __launch_bounds__(256) void gemm_conv_q(
    const ushort* __restrict__ Ah, const ushort* __restrict__ Al,
    const ushort* __restrict__ Bh, const ushort* __restrict__ Bl,
    const float* __restrict__ bias, ushort* __restrict__ fuse,
    ushort* __restrict__ qk_h, ushort* __restrict__ qk_l) {
  const int lane = threadIdx.x & 63, wv = threadIdx.x >> 6;
  const int r = lane & 15, g = lane >> 4;
  const int row0 = blockIdx.x * 64 + wv * 16;
  const ushort* arh = Ah + (size_t)(row0 + r) * 256 + g * 8;
  const ushort* arl = Al + (size_t)(row0 + r) * 256 + g * 8;
  f32x4 acc[16];
#pragma unroll
  for (int i = 0; i < 16; ++i) acc[i] = f32x4{0.f, 0.f, 0.f, 0.f};
#pragma unroll
  for (int kc = 0; kc < 8; ++kc) {
    short8 ah = *(const short8*)(arh + kc * 32);
    short8 al = *(const short8*)(arl + kc * 32);
    const ushort* bbh = Bh + r * 256 + kc * 32 + g * 8;
    const ushort* bbl = Bl + r * 256 + kc * 32 + g * 8;
#pragma unroll
    for (int nt = 0; nt < 16; ++nt) {
      short8 bh = *(const short8*)(bbh + nt * 16 * 256);
      short8 bl = *(const short8*)(bbl + nt * 16 * 256);
      acc[nt] = mfma16(ah, bh, acc[nt]);
      acc[nt] = mfma16(al, bh, acc[nt]);
      acc[nt] = mfma16(ah, bl, acc[nt]);
    }
  }
  const int qr = row0 + g * 4;
#pragma unroll
  for (int nt = 0; nt < 16; ++nt) {
    int n = nt * 16 + r;
    float bs = bias[n];
#pragma unroll
    for (int e = 0; e < 4; ++e) {
      float v = acc[nt][e] + bs;
      int q = qr + e;
      if (n < 128) {
        int b = q / 49, p = q - b * 49;
        fuse[(size_t)b * IN_ + p * 256 + n] = f2bf(v);
      } else {
        size_t j = (size_t)q * 128 + (n - 128);
        ushort h = f2bf(v);
        qk_h[j] = h; qk_l[j] = f2bf(v - bf2f(h));
      }
    }
  }
}

// S variant: n<128 -> svT [128][3136]; n>=128 -> sk hi/lo rows
__global__ __launch_bounds__(256) void gemm_conv_s(
    const ushort* __restrict__ Ah, const ushort* __restrict__ Al,
    const ushort* __restrict__ Bh, const ushort* __restrict__ Bl,
    const float* __restrict__ bias, ushort* __restrict__ svT,
    ushort* __restrict__ sk_h, ushort* __restrict__ sk_l) {
  const int lane = threadIdx.x & 63, wv = threadIdx.x >> 6;
  const int r = lane & 15, g = lane >> 4;
  const int row0 = blockIdx.x * 64 + wv * 16;
  const ushort* arh = Ah + (size_t)(row0 + r) * 256 + g * 8;
  const ushort* arl = Al + (size_t)(row0 + r) * 256 + g * 8;
  f32x4 acc[16];
#pragma unroll
  for (int i = 0; i < 16; ++i) acc[i] = f32x4{0.f, 0.f, 0.f, 0.f};
#pragma unroll
  for (int kc = 0; kc < 8; ++kc) {
    short8 ah = *(const short8*)(arh + kc * 32);
    short8 al = *(const short8*)(arl + kc * 32);
    const ushort* bbh = Bh + r * 256 + kc * 32 + g * 8;
    const ushort* bbl = Bl + r * 256 + kc * 32 + g * 8;
#pragma unroll
    for (int nt = 0; nt < 16; ++nt) {
      short8 bh = *(const short8*)(bbh + nt * 16 * 256);
      short8 bl = *(const short8*)(bbl + nt * 16 * 256);
      acc[nt] = mfma16(ah, bh, acc[nt]);
      acc[nt] = mfma16(al, bh, acc[nt]);
      acc[nt] = mfma16(ah, bl, acc[nt]);
    }
  }
  const int qr = row0 + g * 4;
#pragma unroll
  for (int nt = 0; nt < 16; ++nt) {
    int n = nt * 16 + r;
    float bs = bias[n];
#pragma unroll
    for (int e = 0; e < 4; ++e) {
      float v = acc[nt][e] + bs;
      int k = qr + e;
      if (n < 128) {
        svT[(size_t)n * M_S + k] = f2bf(v);
      } else {
        size_t j = (size_t)k * 128 + (n - 128);
        ushort h = f2bf(v);
        sk_h[j] = h; sk_l[j] = f2bf(v - bf2f(h));
      }
    }
  }
}

// ---------------- fused attention, key-split NZ=4 ----------------
// 1 wave per 32 q-rows x 1 key-chunk; writes partial (num, den).
__global__ __launch_bounds__(64) void attn_kernel(
    const ushort* __restrict__ Qh, const ushort* __restrict__ Ql,
    const ushort* __restrict__ Kh, const ushort* __restrict__ Kl,
    const ushort* __restrict__ Vt, float* __restrict__ pnum,
    float* __restrict__ pden) {
  __shared__ ushort plds[2][16][32];
  const int lane = threadIdx.x;
  const int r = lane & 15, g = lane >> 4;
  const int q0 = blockIdx.x * 32;
  const int z = blockIdx.y;
  const int t0 = z * 24 + (z < 2 ? z : 2);
  const int tn = 24 + (z < 2 ? 1 : 0);

  short8 aqh[2][4], aql[2][4];
#pragma unroll
  for (int mt = 0; mt < 2; ++mt)
#pragma unroll
    for (int kc = 0; kc < 4; ++kc) {
      const int rowq = q0 + mt * 16 + r;
      aqh[mt][kc] = *(const short8*)(Qh + (size_t)rowq * 128 + kc * 32 + g * 8);
      aql[mt][kc] = *(const short8*)(Ql + (size_t)rowq * 128 + kc * 32 + g * 8);
    }

  f32x4 acc[2][8];
#pragma unroll
  for (int mt = 0; mt < 2; ++mt)
#pragma unroll
    for (int ct = 0; ct < 8; ++ct) acc[mt][ct] = f32x4{0.f, 0.f, 0.f, 0.f};
  float den[2][4];
#pragma unroll
  for (int mt = 0; mt < 2; ++mt)
#pragma unroll
    for (int e = 0; e < 4; ++e) den[mt][e] = 0.f;

  for (int t = t0; t < t0 + tn; ++t) {
    const int kb = t * 32;
    f32x4 lg[2][2];
#pragma unroll
    for (int kt = 0; kt < 2; ++kt) {
      const int krow = kb + kt * 16 + r;
      short8 bh[4], bl[4];
#pragma unroll
      for (int kc = 0; kc < 4; ++kc) {
        bh[kc] = *(const short8*)(Kh + (size_t)krow * 128 + kc * 32 + g * 8);
        bl[kc] = *(const short8*)(Kl + (size_t)krow * 128 + kc * 32 + g * 8);
      }
#pragma unroll
      for (int mt = 0; mt < 2; ++mt) {
        f32x4 c = f32x4{0.f, 0.f, 0.f, 0.f};
#pragma unroll
        for (int kc = 0; kc < 4; ++kc) {
          c = mfma16(aqh[mt][kc], bh[kc], c);
          c = mfma16(aql[mt][kc], bh[kc], c);
          c = mfma16(aqh[mt][kc], bl[kc], c);
        }
        lg[mt][kt] = c;
      }
    }
#pragma unroll
    for (int mt = 0; mt < 2; ++mt)
#pragma unroll
      for (int kt = 0; kt < 2; ++kt)
#pragma unroll
        for (int e = 0; e < 4; ++e) {
          float p = __expf(lg[mt][kt][e] - SHIFTC);
          den[mt][e] += p;
          plds[mt][g * 4 + e][kt * 16 + r] = f2bf(p);
        }
    __syncthreads();
#pragma unroll
    for (int mt = 0; mt < 2; ++mt) {
      short8 pf = *(const short8*)(&plds[mt][r][g * 8]);
#pragma unroll
      for (int ct = 0; ct < 8; ++ct) {
        short8 vf = *(const short8*)(Vt + (size_t)(ct * 16 + r) * M_S + kb + g * 8);
        acc[mt][ct] = mfma16(pf, vf, acc[mt][ct]);
      }
    }
    __syncthreads();
  }

#pragma unroll
  for (int mt = 0; mt < 2; ++mt)
#pragma unroll
    for (int e = 0; e < 4; ++e) {
      float d = den[mt][e];
      d += __shfl_xor(d, 1);
      d += __shfl_xor(d, 2);
      d += __shfl_xor(d, 4);
      d += __shfl_xor(d, 8);
      den[mt][e] = d;
    }
#pragma unroll
  for (int mt = 0; mt < 2; ++mt)
#pragma unroll
    for (int ct = 0; ct < 8; ++ct)
#pragma unroll
      for (int e = 0; e < 4; ++e) {
        int q = q0 + mt * 16 + g * 4 + e;
        int c = ct * 16 + r;
        pnum[((size_t)z * M_Q + q) * 128 + c] = acc[mt][ct][e];
      }
  if (r == 0) {
#pragma unroll
    for (int mt = 0; mt < 2; ++mt)
#pragma unroll
      for (int e = 0; e < 4; ++e)
        pden[(size_t)z * M_Q + q0 + mt * 16 + g * 4 + e] = den[mt][e];
  }
}

// combine key-split partials -> att half of fuse (token-major, coalesced)
typedef ushort ushort4v __attribute__((ext_vector_type(4)));
__global__ void attn_reduce(const float* __restrict__ pnum, const float* __restrict__ pden,
                            ushort* __restrict__ fuse) {
  int idx = blockIdx.x * 256 + threadIdx.x;  // exactly 25088*32 (c-quads)
  int q = idx >> 5;
  int c4 = (idx & 31) * 4;
  float4 s = {0.f, 0.f, 0.f, 0.f};
  float d = 0.f;
#pragma unroll
  for (int z = 0; z < NZ; ++z) {
    float4 v = *(const float4*)(pnum + ((size_t)z * M_Q + q) * 128 + c4);
    s.x += v.x; s.y += v.y; s.z += v.z; s.w += v.w;
    d += pden[(size_t)z * M_Q + q];
  }
  float inv = 1.0f / d;
  int b = q / 49, p = q - b * 49;
  ushort4v o;
  o[0] = f2bf(s.x * inv); o[1] = f2bf(s.y * inv);
  o[2] = f2bf(s.z * inv); o[3] = f2bf(s.w * inv);
  *(ushort4v*)(fuse + (size_t)b * IN_ + p * 256 + 128 + c4) = o;
}

// ---------------- fc6: [512][12544] x W6p[2048][12544]^T bf16, K-split FZ=8 -----
__global__ __launch_bounds__(256) void fc6_kernel(
    const ushort* __restrict__ fuse, const ushort* __restrict__ W6p,
    float* __restrict__ part) {
  const int lane = threadIdx.x & 63, wv = threadIdx.x >> 6;
  const int r = lane & 15, g = lane >> 4;
  const int m0 = wv * 128;
  const int n0 = blockIdx.x * 64;
  const int kz = blockIdx.y;
  const int k0 = kz * 1568;
  f32x4 acc[8][4];
#pragma unroll
  for (int mt = 0; mt < 8; ++mt)
#pragma unroll
    for (int nt = 0; nt < 4; ++nt) acc[mt][nt] = f32x4{0.f, 0.f, 0.f, 0.f};
  const ushort* wrow[4];
#pragma unroll
  for (int nt = 0; nt < 4; ++nt)
    wrow[nt] = W6p + (size_t)(n0 + nt * 16 + r) * IN_;
  for (int kk = 0; kk < 1568; kk += 32) {
    const int kcol = k0 + kk + g * 8;
    short8 af[8];
#pragma unroll
    for (int mt = 0; mt < 8; ++mt)
      af[mt] = *(const short8*)(fuse + (size_t)(m0 + mt * 16 + r) * IN_ + kcol);
    short8 bfr[4];
#pragma unroll
    for (int nt = 0; nt < 4; ++nt) bfr[nt] = *(const short8*)(wrow[nt] + kcol);
#pragma unroll
    for (int mt = 0; mt < 8; ++mt)
#pragma unroll
      for (int nt = 0; nt < 4; ++nt) acc[mt][nt] = mfma16(af[mt], bfr[nt], acc[mt][nt]);
  }
#pragma unroll
  for (int mt = 0; mt < 8; ++mt)
#pragma unroll
    for (int nt = 0; nt < 4; ++nt)
#pragma unroll
      for (int e = 0; e < 4; ++e) {
        int m = m0 + mt * 16 + g * 4 + e;
        int n = n0 + nt * 16 + r;
        part[(size_t)kz * 1048576 + (size_t)m * 2048 + n] = acc[mt][nt][e];
      }
}

// sum split-K partials + bias + relu -> X7 bf16 [512][2048]
__global__ void fc6_reduce(const float* __restrict__ part, const float* __restrict__ b6c,
                           const float* __restrict__ b6r, ushort* __restrict__ X7) {
  int idx = blockIdx.x * 256 + threadIdx.x;  // exactly 512*2048
  int n = idx & 2047;
  float s = 0.f;
#pragma unroll
  for (int z = 0; z < FZ; ++z) s += part[(size_t)z * 1048576 + idx];
  s += (n < 1024) ? b6c[n] : b6r[n - 1024];
  s = fmaxf(s, 0.f);
  X7[idx] = f2bf(s);
}

// ---------------- fc7: [512][1024] x W7p[2048][1024]^T bf16 per half ------------
__global__ __launch_bounds__(256) void fc7_kernel(
    const ushort* __restrict__ X7, const ushort* __restrict__ W7p,
    const float* __restrict__ b7c, const float* __restrict__ b7r,
    float* __restrict__ out) {
  const int lane = threadIdx.x & 63, wv = threadIdx.x >> 6;
  const int r = lane & 15, g = lane >> 4;
  const int m0 = blockIdx.x * 64 + wv * 16;
  const int n0 = blockIdx.y * 64;
  const int half = (n0 >= 1024) ? 1 : 0;
  const int nn0 = n0 - half * 1024;
  const float* b7 = half ? b7r : b7c;
  f32x4 acc[4];
#pragma unroll
  for (int nt = 0; nt < 4; ++nt) acc[nt] = f32x4{0.f, 0.f, 0.f, 0.f};
  const ushort* arow = X7 + (size_t)(m0 + r) * 2048 + half * 1024;
  for (int kk = 0; kk < 1024; kk += 32) {
    short8 a = *(const short8*)(arow + kk + g * 8);
#pragma unroll
    for (int nt = 0; nt < 4; ++nt) {
      short8 bb = *(const short8*)(W7p + (size_t)(half * 1024 + nn0 + nt * 16 + r) * 1024 + kk + g * 8);
      acc[nt] = mfma16(a, bb, acc[nt]);
    }
  }
  float* obase = out + (size_t)half * 524288;
#pragma unroll
  for (int nt = 0; nt < 4; ++nt) {
#pragma unroll
    for (int e = 0; e < 4; ++e) {
      int m = m0 + g * 4 + e;
      int n = nn0 + nt * 16 + r;
      obase[(size_t)m * 1024 + n] = fmaxf(acc[nt][e] + b7[n], 0.f);
    }
  }
}

// ---------------- launch ----------------
extern "C" void kernel_launch(void* const* d_in, const int* in_sizes, int n_in,
                              void* d_out, int out_size, void* d_ws, size_t ws_size,
                              hipStream_t stream) {
  const float* x    = (const float*)d_in[0];
  const float* sup  = (const float*)d_in[1];
  const float* Wqv  = (const float*)d_in[2];
  const float* bqv  = (const float*)d_in[3];
  const float* Wqk  = (const float*)d_in[4];
  const float* bqk  = (const float*)d_in[5];
  const float* Wsv  = (const float*)d_in[6];
  const float* bsv  = (const float*)d_in[7];
  const float* Wsk  = (const float*)d_in[8];
  const float* bsk  = (const float*)d_in[9];
  const float* W6c  = (const float*)d_in[10];
  const float* b6c  = (const float*)d_in[11];
  const float* W7c  = (const float*)d_in[12];
  const float* b7c  = (const float*)d_in[13];
  const float* W6r  = (const float*)d_in[14];
  const float* b6r  = (const float*)d_in[15];
  const float* W7r  = (const float*)d_in[16];
  const float* b7r  = (const float*)d_in[17];
  float* out = (float*)d_out;

  char* base = (char*)d_ws;
  size_t off = 0;
  auto alloc = [&](size_t bytes) {
    char* p = base + off;
    off += (bytes + 255) & ~(size_t)255;
    return p;
  };
  // Region A: stage 1 = Xp/Xs hi/lo (28.9MB); stage 2 (after convs) = W6p+W7p (55.6MB)
  char* regionA = alloc((size_t)2048 * IN_ * 2 + (size_t)2048 * 1024 * 2);
  ushort* Xp_h = (ushort*)(regionA);
  ushort* Xp_l = (ushort*)(regionA + 12845056);
  ushort* Xs_h = (ushort*)(regionA + 25690112);
  ushort* Xs_l = (ushort*)(regionA + 27295744);
  ushort* W6p  = (ushort*)(regionA);
  ushort* W7p  = (ushort*)(regionA + (size_t)2048 * IN_ * 2);
  // Region B: attn pnum (51.4MB) then fc6 part (33.6MB)
  char* regionB = alloc((size_t)NZ * M_Q * 128 * 4);
  float* pnum = (float*)regionB;
  float* part = (float*)regionB;
  // Persistent region
  ushort* Wq_h = (ushort*)alloc(65536 * 2);
  ushort* Wq_l = (ushort*)alloc(65536 * 2);
  ushort* Ws_h = (ushort*)alloc(65536 * 2);
  ushort* Ws_l = (ushort*)alloc(65536 * 2);
  float*  biasq = (float*)alloc(256 * 4);
  float*  biass = (float*)alloc(256 * 4);
  ushort* fuse = (ushort*)alloc((size_t)512 * IN_ * 2);
  ushort* qk_h = (ushort*)alloc((size_t)M_Q * 128 * 2);
  ushort* qk_l = (ushort*)alloc((size_t)M_Q * 128 * 2);
  ushort* sk_h = (ushort*)alloc((size_t)M_S * 128 * 2);
  ushort* sk_l = (ushort*)alloc((size_t)M_S * 128 * 2);
  ushort* svT  = (ushort*)alloc((size_t)M_S * 128 * 2);
  float*  pden = (float*)alloc((size_t)NZ * M_Q * 4);
  ushort* X7   = (ushort*)alloc((size_t)512 * 2048 * 2);
  if (off > ws_size) return;  // insufficient scratch; validation will show poison

  // 1) coalesced transpose+pack to bf16 hi/lo, token-major
  transpose_pack<<<dim3(512, 1), dim3(256), 0, stream>>>(x, Xp_h, Xp_l, 49);
  transpose_pack<<<dim3(16, 4), dim3(256), 0, stream>>>(sup, Xs_h, Xs_l, 196);
  pack_w<<<dim3(515), dim3(256), 0, stream>>>(Wqv, Wqk, bqv, bqk, Wsv, Wsk, bsv, bsk,
                                              Wq_h, Wq_l, biasq, Ws_h, Ws_l, biass);
  // 2) 1x1 convs with fused repack epilogues
  gemm_conv_q<<<dim3(392), dim3(256), 0, stream>>>(Xp_h, Xp_l, Wq_h, Wq_l, biasq,
                                                   fuse, qk_h, qk_l);
  gemm_conv_s<<<dim3(49), dim3(256), 0, stream>>>(Xs_h, Xs_l, Ws_h, Ws_l, biass,
                                                  svT, sk_h, sk_l);
  // 3) pack MLP weights to bf16 into regionA (Xp/Xs now dead)
  pack_w6<<<dim3(2048), dim3(256), 0, stream>>>(W6c, W6r, W6p);
  pack_w7<<<dim3(8192), dim3(256), 0, stream>>>(W7c, W7r, W7p);
  // 4) fused attention (key-split) + combine
  attn_kernel<<<dim3(784, NZ), dim3(64), 0, stream>>>(qk_h, qk_l, sk_h, sk_l, svT,
                                                      pnum, pden);
  attn_reduce<<<dim3(3136), dim3(256), 0, stream>>>(pnum, pden, fuse);
  // 5) fc6 (K-split deterministic) + reduce+relu
  fc6_kernel<<<dim3(32, FZ), dim3(256), 0, stream>>>(fuse, W6p, part);
  fc6_reduce<<<dim3(4096), dim3(256), 0, stream>>>(part, b6c, b6r, X7);
  // 6) fc7 + bias + relu -> d_out (xc then xr)
  fc7_kernel<<<dim3(8, 32), dim3(256), 0, stream>>>(X7, W7p, b7c, b7r, out);
}

// Round 4
// 532.054 us; speedup vs baseline: 1.8645x; 1.1208x over previous
//
#include <hip/hip_runtime.h>
#include <hip/hip_bf16.h>
#include <stdint.h>

typedef short short8 __attribute__((ext_vector_type(8)));
typedef float f32x4 __attribute__((ext_vector_type(4)));

#define M_Q   25088   // B*H*W = 512*49
#define M_S   3136    // NS*HS*WS = 16*196
#define IN_   12544
#define SHIFTC 40.0f
#define NZ    4       // attention key-split
#define FZ    8       // fc6 K-split

__device__ __forceinline__ ushort f2bf(float f) {
  union { float f; uint32_t u; } v; v.f = f;
  uint32_t r = v.u + 0x7fffu + ((v.u >> 16) & 1u);
  return (ushort)(r >> 16);
}
__device__ __forceinline__ float bf2f(ushort u) {
  union { uint32_t u; float f; } v; v.u = ((uint32_t)u) << 16;
  return v.f;
}
__device__ __forceinline__ f32x4 mfma16(short8 a, short8 b, f32x4 c) {
  return __builtin_amdgcn_mfma_f32_16x16x32_bf16(a, b, c, 0, 0, 0);
}

// ---------------- coalesced transpose+pack: [B][256][P] f32 -> [B*P][256] hi/lo bf16
__global__ __launch_bounds__(256) void transpose_pack(
    const float* __restrict__ src, ushort* __restrict__ hi,
    ushort* __restrict__ lo, int P) {
  const int b = blockIdx.x;
  const int p0 = blockIdx.y * 49;
  const int w = threadIdx.x >> 6, l = threadIdx.x & 63;
  if (l >= 49) return;
  const int p = p0 + l;
  const float* sb = src + (size_t)b * 256 * P + p;
  const size_t orow = ((size_t)b * P + p) * 256;
#pragma unroll
  for (int ch = 0; ch < 8; ++ch) {
    const int c0 = (ch * 4 + w) * 8;
    short8 h8, l8;
#pragma unroll
    for (int j = 0; j < 8; ++j) {
      float v = sb[(size_t)(c0 + j) * P];
      ushort h = f2bf(v);
      h8[j] = (short)h;
      l8[j] = (short)f2bf(v - bf2f(h));
    }
    *(short8*)(hi + orow + c0) = h8;
    *(short8*)(lo + orow + c0) = l8;
  }
}

// stack conv weights [128,256]+[128,256] -> [256,256] hi/lo, plus biases
__global__ void pack_w(const float* __restrict__ Wqv, const float* __restrict__ Wqk,
                       const float* __restrict__ bqv, const float* __restrict__ bqk,
                       const float* __restrict__ Wsv, const float* __restrict__ Wsk,
                       const float* __restrict__ bsv, const float* __restrict__ bsk,
                       ushort* __restrict__ Wq_h, ushort* __restrict__ Wq_l, float* __restrict__ biasq,
                       ushort* __restrict__ Ws_h, ushort* __restrict__ Ws_l, float* __restrict__ biass) {
  int idx = blockIdx.x * 256 + threadIdx.x;
  if (idx < 65536) {
    int n = idx >> 8;
    const float* W = (n < 128) ? (Wqv + n * 256) : (Wqk + (n - 128) * 256);
    float v = W[idx & 255];
    ushort h = f2bf(v);
    Wq_h[idx] = h; Wq_l[idx] = f2bf(v - bf2f(h));
  } else if (idx < 131072) {
    int j = idx - 65536;
    int n = j >> 8;
    const float* W = (n < 128) ? (Wsv + n * 256) : (Wsk + (n - 128) * 256);
    float v = W[j & 255];
    ushort h = f2bf(v);
    Ws_h[j] = h; Ws_l[j] = f2bf(v - bf2f(h));
  } else if (idx < 131328) {
    int n = idx - 131072;
    biasq[n] = (n < 128) ? bqv[n] : bqk[n - 128];
  } else if (idx < 131584) {
    int n = idx - 131328;
    biass[n] = (n < 128) ? bsv[n] : bsk[n - 128];
  }
}

// W6 [n][c*49+p] f32 -> W6p [n][p*256+c] bf16 (one block per n, coalesced reads)
__global__ __launch_bounds__(256) void pack_w6(
    const float* __restrict__ W6c, const float* __restrict__ W6r,
    ushort* __restrict__ W6p) {
  const int n = blockIdx.x;
  const float* src = (n < 1024) ? (W6c + (size_t)n * IN_)
                                : (W6r + (size_t)(n - 1024) * IN_);
  ushort* dst = W6p + (size_t)n * IN_;
  for (int j = 0; j < 49; ++j) {
    int i = j * 256 + threadIdx.x;        // coalesced read index
    float v = src[i];
    int c = i / 49;
    int p = i - c * 49;
    dst[p * 256 + c] = f2bf(v);
  }
}

// W7 -> bf16 [2048][1024] (xc rows then xr rows)
__global__ void pack_w7(const float* __restrict__ W7c, const float* __restrict__ W7r,
                        ushort* __restrict__ W7p) {
  int idx = blockIdx.x * 256 + threadIdx.x;  // exactly 2048*1024
  float v = (idx < 1048576) ? W7c[idx] : W7r[idx - 1048576];
  W7p[idx] = f2bf(v);
}

// ---------------- conv GEMM (split-bf16, 3-term) + fused repack epilogues -------
// Q variant: n<128 -> fuse qv half (token-major [b][p][c]); n>=128 -> qk hi/lo rows
__global__ __launch_bounds__(256) void gemm_conv_q(
    const ushort* __restrict__ Ah, const ushort* __restrict__ Al,
    const ushort* __restrict__ Bh, const ushort* __restrict__ Bl,
    const float* __restrict__ bias, ushort* __restrict__ fuse,
    ushort* __restrict__ qk_h, ushort* __restrict__ qk_l) {
  const int lane = threadIdx.x & 63, wv = threadIdx.x >> 6;
  const int r = lane & 15, g = lane >> 4;
  const int row0 = blockIdx.x * 64 + wv * 16;
  const ushort* arh = Ah + (size_t)(row0 + r) * 256 + g * 8;
  const ushort* arl = Al + (size_t)(row0 + r) * 256 + g * 8;
  f32x4 acc[16];
#pragma unroll
  for (int i = 0; i < 16; ++i) acc[i] = f32x4{0.f, 0.f, 0.f, 0.f};
#pragma unroll
  for (int kc = 0; kc < 8; ++kc) {
    short8 ah = *(const short8*)(arh + kc * 32);
    short8 al = *(const short8*)(arl + kc * 32);
    const ushort* bbh = Bh + r * 256 + kc * 32 + g * 8;
    const ushort* bbl = Bl + r * 256 + kc * 32 + g * 8;
#pragma unroll
    for (int nt = 0; nt < 16; ++nt) {
      short8 bh = *(const short8*)(bbh + nt * 16 * 256);
      short8 bl = *(const short8*)(bbl + nt * 16 * 256);
      acc[nt] = mfma16(ah, bh, acc[nt]);
      acc[nt] = mfma16(al, bh, acc[nt]);
      acc[nt] = mfma16(ah, bl, acc[nt]);
    }
  }
  const int qr = row0 + g * 4;
#pragma unroll
  for (int nt = 0; nt < 16; ++nt) {
    int n = nt * 16 + r;
    float bs = bias[n];
#pragma unroll
    for (int e = 0; e < 4; ++e) {
      float v = acc[nt][e] + bs;
      int q = qr + e;
      if (n < 128) {
        int b = q / 49, p = q - b * 49;
        fuse[(size_t)b * IN_ + p * 256 + n] = f2bf(v);
      } else {
        size_t j = (size_t)q * 128 + (n - 128);
        ushort h = f2bf(v);
        qk_h[j] = h; qk_l[j] = f2bf(v - bf2f(h));
      }
    }
  }
}

// S variant: n<128 -> svT [128][3136]; n>=128 -> sk hi/lo rows
__global__ __launch_bounds__(256) void gemm_conv_s(
    const ushort* __restrict__ Ah, const ushort* __restrict__ Al,
    const ushort* __restrict__ Bh, const ushort* __restrict__ Bl,
    const float* __restrict__ bias, ushort* __restrict__ svT,
    ushort* __restrict__ sk_h, ushort* __restrict__ sk_l) {
  const int lane = threadIdx.x & 63, wv = threadIdx.x >> 6;
  const int r = lane & 15, g = lane >> 4;
  const int row0 = blockIdx.x * 64 + wv * 16;
  const ushort* arh = Ah + (size_t)(row0 + r) * 256 + g * 8;
  const ushort* arl = Al + (size_t)(row0 + r) * 256 + g * 8;
  f32x4 acc[16];
#pragma unroll
  for (int i = 0; i < 16; ++i) acc[i] = f32x4{0.f, 0.f, 0.f, 0.f};
#pragma unroll
  for (int kc = 0; kc < 8; ++kc) {
    short8 ah = *(const short8*)(arh + kc * 32);
    short8 al = *(const short8*)(arl + kc * 32);
    const ushort* bbh = Bh + r * 256 + kc * 32 + g * 8;
    const ushort* bbl = Bl + r * 256 + kc * 32 + g * 8;
#pragma unroll
    for (int nt = 0; nt < 16; ++nt) {
      short8 bh = *(const short8*)(bbh + nt * 16 * 256);
      short8 bl = *(const short8*)(bbl + nt * 16 * 256);
      acc[nt] = mfma16(ah, bh, acc[nt]);
      acc[nt] = mfma16(al, bh, acc[nt]);
      acc[nt] = mfma16(ah, bl, acc[nt]);
    }
  }
  const int qr = row0 + g * 4;
#pragma unroll
  for (int nt = 0; nt < 16; ++nt) {
    int n = nt * 16 + r;
    float bs = bias[n];
#pragma unroll
    for (int e = 0; e < 4; ++e) {
      float v = acc[nt][e] + bs;
      int k = qr + e;
      if (n < 128) {
        svT[(size_t)n * M_S + k] = f2bf(v);
      } else {
        size_t j = (size_t)k * 128 + (n - 128);
        ushort h = f2bf(v);
        sk_h[j] = h; sk_l[j] = f2bf(v - bf2f(h));
      }
    }
  }
}

// ---------------- fused attention, 4-wave blocks + LDS-staged K/V ----------------
// block = 256 thr = 4 waves; 128 q-rows/block (32/wave); key chunk z of NZ.
// K LDS: [row][chunk^ (row&7)] 16B-chunk swizzle (ideal banks both sides).
// V LDS: [c][k] linear (64B row stride -> ideal banks both sides).
__global__ __launch_bounds__(256) void attn_kernel(
    const ushort* __restrict__ Qh, const ushort* __restrict__ Ql,
    const ushort* __restrict__ Kh, const ushort* __restrict__ Kl,
    const ushort* __restrict__ Vt, float* __restrict__ pnum,
    float* __restrict__ pden) {
  __shared__ ushort khs[32 * 128];
  __shared__ ushort kls[32 * 128];
  __shared__ ushort vvs[128 * 32];
  __shared__ ushort plds[4 * 2 * 16 * 32];
  const int tid = threadIdx.x;
  const int w = tid >> 6, lane = tid & 63;
  const int r = lane & 15, g = lane >> 4;
  const int q0 = blockIdx.x * 128 + w * 32;
  const int z = blockIdx.y;
  const int t0 = z * 24 + (z < 2 ? z : 2);
  const int tn = 24 + (z < 2 ? 1 : 0);
  ushort* pw = plds + w * 1024;

  short8 aqh[2][4], aql[2][4];
#pragma unroll
  for (int mt = 0; mt < 2; ++mt)
#pragma unroll
    for (int kc = 0; kc < 4; ++kc) {
      const int rowq = q0 + mt * 16 + r;
      aqh[mt][kc] = *(const short8*)(Qh + (size_t)rowq * 128 + kc * 32 + g * 8);
      aql[mt][kc] = *(const short8*)(Ql + (size_t)rowq * 128 + kc * 32 + g * 8);
    }

  f32x4 acc[2][8];
#pragma unroll
  for (int mt = 0; mt < 2; ++mt)
#pragma unroll
    for (int ct = 0; ct < 8; ++ct) acc[mt][ct] = f32x4{0.f, 0.f, 0.f, 0.f};
  float den[2][4];
#pragma unroll
  for (int mt = 0; mt < 2; ++mt)
#pragma unroll
    for (int e = 0; e < 4; ++e) den[mt][e] = 0.f;

  for (int t = t0; t < t0 + tn; ++t) {
    const int kb = t * 32;
    __syncthreads();  // readers done with previous tile
    // ---- stage K(hi/lo) swizzled + V linear; coalesced 16B/lane ----
#pragma unroll
    for (int i = 0; i < 2; ++i) {
      const int chunk = i * 256 + tid;
      const int row = chunk >> 4, c8 = chunk & 15;
      short8 dh = *(const short8*)(Kh + (size_t)(kb + row) * 128 + c8 * 8);
      short8 dl = *(const short8*)(Kl + (size_t)(kb + row) * 128 + c8 * 8);
      const int loff = row * 128 + ((c8 ^ (row & 7)) << 3);
      *(short8*)(khs + loff) = dh;
      *(short8*)(kls + loff) = dl;
      const int c = chunk >> 2, kc2 = chunk & 3;
      short8 dv = *(const short8*)(Vt + (size_t)c * M_S + kb + kc2 * 8);
      *(short8*)(vvs + c * 32 + kc2 * 8) = dv;
    }
    __syncthreads();  // tile ready

    // ---- QK^T from LDS (3-term split-bf16) ----
    f32x4 lg[2][2];
#pragma unroll
    for (int kt = 0; kt < 2; ++kt) {
      const int rowk = kt * 16 + r;
      const int kbase = rowk * 128;
      short8 bh[4], bl[4];
#pragma unroll
      for (int kc = 0; kc < 4; ++kc) {
        const int pos = kbase + (((kc * 4 + g) ^ (rowk & 7)) << 3);
        bh[kc] = *(const short8*)(khs + pos);
        bl[kc] = *(const short8*)(kls + pos);
      }
#pragma unroll
      for (int mt = 0; mt < 2; ++mt) {
        f32x4 c = f32x4{0.f, 0.f, 0.f, 0.f};
#pragma unroll
        for (int kc = 0; kc < 4; ++kc) {
          c = mfma16(aqh[mt][kc], bh[kc], c);
          c = mfma16(aql[mt][kc], bh[kc], c);
          c = mfma16(aqh[mt][kc], bl[kc], c);
        }
        lg[mt][kt] = c;
      }
    }
    // ---- exp, den partials, stash P (per-wave LDS slice, no barrier) ----
#pragma unroll
    for (int mt = 0; mt < 2; ++mt)
#pragma unroll
      for (int kt = 0; kt < 2; ++kt)
#pragma unroll
        for (int e = 0; e < 4; ++e) {
          float p = __expf(lg[mt][kt][e] - SHIFTC);
          den[mt][e] += p;
          pw[mt * 512 + (g * 4 + e) * 32 + kt * 16 + r] = f2bf(p);
        }
    // ---- PV from LDS ----
#pragma unroll
    for (int mt = 0; mt < 2; ++mt) {
      short8 pf = *(const short8*)(pw + mt * 512 + r * 32 + g * 8);
#pragma unroll
      for (int ct = 0; ct < 8; ++ct) {
        short8 vf = *(const short8*)(vvs + (ct * 16 + r) * 32 + g * 8);
        acc[mt][ct] = mfma16(pf, vf, acc[mt][ct]);
      }
    }
  }

#pragma unroll
  for (int mt = 0; mt < 2; ++mt)
#pragma unroll
    for (int e = 0; e < 4; ++e) {
      float d = den[mt][e];
      d += __shfl_xor(d, 1);
      d += __shfl_xor(d, 2);
      d += __shfl_xor(d, 4);
      d += __shfl_xor(d, 8);
      den[mt][e] = d;
    }
#pragma unroll
  for (int mt = 0; mt < 2; ++mt)
#pragma unroll
    for (int ct = 0; ct < 8; ++ct)
#pragma unroll
      for (int e = 0; e < 4; ++e) {
        int q = q0 + mt * 16 + g * 4 + e;
        int c = ct * 16 + r;
        pnum[((size_t)z * M_Q + q) * 128 + c] = acc[mt][ct][e];
      }
  if (r == 0) {
#pragma unroll
    for (int mt = 0; mt < 2; ++mt)
#pragma unroll
      for (int e = 0; e < 4; ++e)
        pden[(size_t)z * M_Q + q0 + mt * 16 + g * 4 + e] = den[mt][e];
  }
}

// combine key-split partials -> att half of fuse (token-major, coalesced)
typedef ushort ushort4v __attribute__((ext_vector_type(4)));
__global__ void attn_reduce(const float* __restrict__ pnum, const float* __restrict__ pden,
                            ushort* __restrict__ fuse) {
  int idx = blockIdx.x * 256 + threadIdx.x;  // exactly 25088*32 (c-quads)
  int q = idx >> 5;
  int c4 = (idx & 31) * 4;
  float4 s = {0.f, 0.f, 0.f, 0.f};
  float d = 0.f;
#pragma unroll
  for (int z = 0; z < NZ; ++z) {
    float4 v = *(const float4*)(pnum + ((size_t)z * M_Q + q) * 128 + c4);
    s.x += v.x; s.y += v.y; s.z += v.z; s.w += v.w;
    d += pden[(size_t)z * M_Q + q];
  }
  float inv = 1.0f / d;
  int b = q / 49, p = q - b * 49;
  ushort4v o;
  o[0] = f2bf(s.x * inv); o[1] = f2bf(s.y * inv);
  o[2] = f2bf(s.z * inv); o[3] = f2bf(s.w * inv);
  *(ushort4v*)(fuse + (size_t)b * IN_ + p * 256 + 128 + c4) = o;
}

// ---------------- fc6: [512][12544] x W6p[2048][12544]^T bf16, K-split FZ=8 -----
__global__ __launch_bounds__(256) void fc6_kernel(
    const ushort* __restrict__ fuse, const ushort* __restrict__ W6p,
    float* __restrict__ part) {
  const int lane = threadIdx.x & 63, wv = threadIdx.x >> 6;
  const int r = lane & 15, g = lane >> 4;
  const int m0 = wv * 128;
  const int n0 = blockIdx.x * 64;
  const int kz = blockIdx.y;
  const int k0 = kz * 1568;
  f32x4 acc[8][4];
#pragma unroll
  for (int mt = 0; mt < 8; ++mt)
#pragma unroll
    for (int nt = 0; nt < 4; ++nt) acc[mt][nt] = f32x4{0.f, 0.f, 0.f, 0.f};
  const ushort* wrow[4];
#pragma unroll
  for (int nt = 0; nt < 4; ++nt)
    wrow[nt] = W6p + (size_t)(n0 + nt * 16 + r) * IN_;
  for (int kk = 0; kk < 1568; kk += 32) {
    const int kcol = k0 + kk + g * 8;
    short8 af[8];
#pragma unroll
    for (int mt = 0; mt < 8; ++mt)
      af[mt] = *(const short8*)(fuse + (size_t)(m0 + mt * 16 + r) * IN_ + kcol);
    short8 bfr[4];
#pragma unroll
    for (int nt = 0; nt < 4; ++nt) bfr[nt] = *(const short8*)(wrow[nt] + kcol);
#pragma unroll
    for (int mt = 0; mt < 8; ++mt)
#pragma unroll
      for (int nt = 0; nt < 4; ++nt) acc[mt][nt] = mfma16(af[mt], bfr[nt], acc[mt][nt]);
  }
#pragma unroll
  for (int mt = 0; mt < 8; ++mt)
#pragma unroll
    for (int nt = 0; nt < 4; ++nt)
#pragma unroll
      for (int e = 0; e < 4; ++e) {
        int m = m0 + mt * 16 + g * 4 + e;
        int n = n0 + nt * 16 + r;
        part[(size_t)kz * 1048576 + (size_t)m * 2048 + n] = acc[mt][nt][e];
      }
}

// sum split-K partials + bias + relu -> X7 bf16 [512][2048]
__global__ void fc6_reduce(const float* __restrict__ part, const float* __restrict__ b6c,
                           const float* __restrict__ b6r, ushort* __restrict__ X7) {
  int idx = blockIdx.x * 256 + threadIdx.x;  // exactly 512*2048
  int n = idx & 2047;
  float s = 0.f;
#pragma unroll
  for (int z = 0; z < FZ; ++z) s += part[(size_t)z * 1048576 + idx];
  s += (n < 1024) ? b6c[n] : b6r[n - 1024];
  s = fmaxf(s, 0.f);
  X7[idx] = f2bf(s);
}

// ---------------- fc7: [512][1024] x W7p[2048][1024]^T bf16 per half ------------
__global__ __launch_bounds__(256) void fc7_kernel(
    const ushort* __restrict__ X7, const ushort* __restrict__ W7p,
    const float* __restrict__ b7c, const float* __restrict__ b7r,
    float* __restrict__ out) {
  const int lane = threadIdx.x & 63, wv = threadIdx.x >> 6;
  const int r = lane & 15, g = lane >> 4;
  const int m0 = blockIdx.x * 64 + wv * 16;
  const int n0 = blockIdx.y * 64;
  const int half = (n0 >= 1024) ? 1 : 0;
  const int nn0 = n0 - half * 1024;
  const float* b7 = half ? b7r : b7c;
  f32x4 acc[4];
#pragma unroll
  for (int nt = 0; nt < 4; ++nt) acc[nt] = f32x4{0.f, 0.f, 0.f, 0.f};
  const ushort* arow = X7 + (size_t)(m0 + r) * 2048 + half * 1024;
  for (int kk = 0; kk < 1024; kk += 32) {
    short8 a = *(const short8*)(arow + kk + g * 8);
#pragma unroll
    for (int nt = 0; nt < 4; ++nt) {
      short8 bb = *(const short8*)(W7p + (size_t)(half * 1024 + nn0 + nt * 16 + r) * 1024 + kk + g * 8);
      acc[nt] = mfma16(a, bb, acc[nt]);
    }
  }
  float* obase = out + (size_t)half * 524288;
#pragma unroll
  for (int nt = 0; nt < 4; ++nt) {
#pragma unroll
    for (int e = 0; e < 4; ++e) {
      int m = m0 + g * 4 + e;
      int n = nn0 + nt * 16 + r;
      obase[(size_t)m * 1024 + n] = fmaxf(acc[nt][e] + b7[n], 0.f);
    }
  }
}

// ---------------- launch ----------------
extern "C" void kernel_launch(void* const* d_in, const int* in_sizes, int n_in,
                              void* d_out, int out_size, void* d_ws, size_t ws_size,
                              hipStream_t stream) {
  const float* x    = (const float*)d_in[0];
  const float* sup  = (const float*)d_in[1];
  const float* Wqv  = (const float*)d_in[2];
  const float* bqv  = (const float*)d_in[3];
  const float* Wqk  = (const float*)d_in[4];
  const float* bqk  = (const float*)d_in[5];
  const float* Wsv  = (const float*)d_in[6];
  const float* bsv  = (const float*)d_in[7];
  const float* Wsk  = (const float*)d_in[8];
  const float* bsk  = (const float*)d_in[9];
  const float* W6c  = (const float*)d_in[10];
  const float* b6c  = (const float*)d_in[11];
  const float* W7c  = (const float*)d_in[12];
  const float* b7c  = (const float*)d_in[13];
  const float* W6r  = (const float*)d_in[14];
  const float* b6r  = (const float*)d_in[15];
  const float* W7r  = (const float*)d_in[16];
  const float* b7r  = (const float*)d_in[17];
  float* out = (float*)d_out;

  char* base = (char*)d_ws;
  size_t off = 0;
  auto alloc = [&](size_t bytes) {
    char* p = base + off;
    off += (bytes + 255) & ~(size_t)255;
    return p;
  };
  // Region A: stage 1 = Xp/Xs hi/lo (28.9MB); stage 2 (after convs) = W6p+W7p (55.6MB)
  char* regionA = alloc((size_t)2048 * IN_ * 2 + (size_t)2048 * 1024 * 2);
  ushort* Xp_h = (ushort*)(regionA);
  ushort* Xp_l = (ushort*)(regionA + 12845056);
  ushort* Xs_h = (ushort*)(regionA + 25690112);
  ushort* Xs_l = (ushort*)(regionA + 27295744);
  ushort* W6p  = (ushort*)(regionA);
  ushort* W7p  = (ushort*)(regionA + (size_t)2048 * IN_ * 2);
  // Region B: attn pnum (51.4MB) then fc6 part (33.6MB)
  char* regionB = alloc((size_t)NZ * M_Q * 128 * 4);
  float* pnum = (float*)regionB;
  float* part = (float*)regionB;
  // Persistent region
  ushort* Wq_h = (ushort*)alloc(65536 * 2);
  ushort* Wq_l = (ushort*)alloc(65536 * 2);
  ushort* Ws_h = (ushort*)alloc(65536 * 2);
  ushort* Ws_l = (ushort*)alloc(65536 * 2);
  float*  biasq = (float*)alloc(256 * 4);
  float*  biass = (float*)alloc(256 * 4);
  ushort* fuse = (ushort*)alloc((size_t)512 * IN_ * 2);
  ushort* qk_h = (ushort*)alloc((size_t)M_Q * 128 * 2);
  ushort* qk_l = (ushort*)alloc((size_t)M_Q * 128 * 2);
  ushort* sk_h = (ushort*)alloc((size_t)M_S * 128 * 2);
  ushort* sk_l = (ushort*)alloc((size_t)M_S * 128 * 2);
  ushort* svT  = (ushort*)alloc((size_t)M_S * 128 * 2);
  float*  pden = (float*)alloc((size_t)NZ * M_Q * 4);
  ushort* X7   = (ushort*)alloc((size_t)512 * 2048 * 2);
  if (off > ws_size) return;  // insufficient scratch; validation will show poison

  // 1) coalesced transpose+pack to bf16 hi/lo, token-major
  transpose_pack<<<dim3(512, 1), dim3(256), 0, stream>>>(x, Xp_h, Xp_l, 49);
  transpose_pack<<<dim3(16, 4), dim3(256), 0, stream>>>(sup, Xs_h, Xs_l, 196);
  pack_w<<<dim3(515), dim3(256), 0, stream>>>(Wqv, Wqk, bqv, bqk, Wsv, Wsk, bsv, bsk,
                                              Wq_h, Wq_l, biasq, Ws_h, Ws_l, biass);
  // 2) 1x1 convs with fused repack epilogues
  gemm_conv_q<<<dim3(392), dim3(256), 0, stream>>>(Xp_h, Xp_l, Wq_h, Wq_l, biasq,
                                                   fuse, qk_h, qk_l);
  gemm_conv_s<<<dim3(49), dim3(256), 0, stream>>>(Xs_h, Xs_l, Ws_h, Ws_l, biass,
                                                  svT, sk_h, sk_l);
  // 3) pack MLP weights to bf16 into regionA (Xp/Xs now dead)
  pack_w6<<<dim3(2048), dim3(256), 0, stream>>>(W6c, W6r, W6p);
  pack_w7<<<dim3(8192), dim3(256), 0, stream>>>(W7c, W7r, W7p);
  // 4) fused attention (4-wave LDS-staged, key-split) + combine
  attn_kernel<<<dim3(196, NZ), dim3(256), 0, stream>>>(qk_h, qk_l, sk_h, sk_l, svT,
                                                       pnum, pden);
  attn_reduce<<<dim3(3136), dim3(256), 0, stream>>>(pnum, pden, fuse);
  // 5) fc6 (K-split deterministic) + reduce+relu
  fc6_kernel<<<dim3(32, FZ), dim3(256), 0, stream>>>(fuse, W6p, part);
  fc6_reduce<<<dim3(4096), dim3(256), 0, stream>>>(part, b6c, b6r, X7);
  // 6) fc7 + bias + relu -> d_out (xc then xr)
  fc7_kernel<<<dim3(8, 32), dim3(256), 0, stream>>>(X7, W7p, b7c, b7r, out);
}

// Round 5
// 420.628 us; speedup vs baseline: 2.3583x; 1.2649x over previous
//
#include <hip/hip_runtime.h>
#include <hip/hip_bf16.h>
#include <stdint.h>

typedef short short8 __attribute__((ext_vector_type(8)));
typedef float f32x4 __attribute__((ext_vector_type(4)));

#define M_Q   25088   // B*H*W = 512*49
#define M_S   3136    // NS*HS*WS = 16*196
#define IN_   12544
#define SHIFTC 40.0f
#define NZ    4       // attention key-split
#define FZ    8       // fc6 K-split
#define PSTR  40      // P-LDS row stride (ushorts), padded vs 32 to break bank conflicts

__device__ __forceinline__ ushort f2bf(float f) {
  union { float f; uint32_t u; } v; v.f = f;
  uint32_t r = v.u + 0x7fffu + ((v.u >> 16) & 1u);
  return (ushort)(r >> 16);
}
__device__ __forceinline__ float bf2f(ushort u) {
  union { uint32_t u; float f; } v; v.u = ((uint32_t)u) << 16;
  return v.f;
}
__device__ __forceinline__ f32x4 mfma16(short8 a, short8 b, f32x4 c) {
  return __builtin_amdgcn_mfma_f32_16x16x32_bf16(a, b, c, 0, 0, 0);
}

// ---------------- coalesced transpose+pack: [B][256][P] f32 -> [B*P][256] hi/lo bf16
__global__ __launch_bounds__(256) void transpose_pack(
    const float* __restrict__ src, ushort* __restrict__ hi,
    ushort* __restrict__ lo, int P) {
  const int b = blockIdx.x;
  const int p0 = blockIdx.y * 49;
  const int w = threadIdx.x >> 6, l = threadIdx.x & 63;
  if (l >= 49) return;
  const int p = p0 + l;
  const float* sb = src + (size_t)b * 256 * P + p;
  const size_t orow = ((size_t)b * P + p) * 256;
#pragma unroll
  for (int ch = 0; ch < 8; ++ch) {
    const int c0 = (ch * 4 + w) * 8;
    short8 h8, l8;
#pragma unroll
    for (int j = 0; j < 8; ++j) {
      float v = sb[(size_t)(c0 + j) * P];
      ushort h = f2bf(v);
      h8[j] = (short)h;
      l8[j] = (short)f2bf(v - bf2f(h));
    }
    *(short8*)(hi + orow + c0) = h8;
    *(short8*)(lo + orow + c0) = l8;
  }
}

// stack conv weights [128,256]+[128,256] -> [256,256] hi/lo, plus biases
__global__ void pack_w(const float* __restrict__ Wqv, const float* __restrict__ Wqk,
                       const float* __restrict__ bqv, const float* __restrict__ bqk,
                       const float* __restrict__ Wsv, const float* __restrict__ Wsk,
                       const float* __restrict__ bsv, const float* __restrict__ bsk,
                       ushort* __restrict__ Wq_h, ushort* __restrict__ Wq_l, float* __restrict__ biasq,
                       ushort* __restrict__ Ws_h, ushort* __restrict__ Ws_l, float* __restrict__ biass) {
  int idx = blockIdx.x * 256 + threadIdx.x;
  if (idx < 65536) {
    int n = idx >> 8;
    const float* W = (n < 128) ? (Wqv + n * 256) : (Wqk + (n - 128) * 256);
    float v = W[idx & 255];
    ushort h = f2bf(v);
    Wq_h[idx] = h; Wq_l[idx] = f2bf(v - bf2f(h));
  } else if (idx < 131072) {
    int j = idx - 65536;
    int n = j >> 8;
    const float* W = (n < 128) ? (Wsv + n * 256) : (Wsk + (n - 128) * 256);
    float v = W[j & 255];
    ushort h = f2bf(v);
    Ws_h[j] = h; Ws_l[j] = f2bf(v - bf2f(h));
  } else if (idx < 131328) {
    int n = idx - 131072;
    biasq[n] = (n < 128) ? bqv[n] : bqk[n - 128];
  } else if (idx < 131584) {
    int n = idx - 131328;
    biass[n] = (n < 128) ? bsv[n] : bsk[n - 128];
  }
}

// W6 [n][c*49+p] f32 -> W6p [n][p*256+c] bf16 via LDS tile (both sides coalesced)
__global__ __launch_bounds__(256) void pack_w6(
    const float* __restrict__ W6c, const float* __restrict__ W6r,
    ushort* __restrict__ W6p) {
  __shared__ ushort tile[IN_];
  const int n = blockIdx.x;
  const float* src = (n < 1024) ? (W6c + (size_t)n * IN_)
                                : (W6r + (size_t)(n - 1024) * IN_);
  ushort* dst = W6p + (size_t)n * IN_;
#pragma unroll 7
  for (int j = 0; j < 49; ++j) {
    int i = j * 256 + threadIdx.x;
    tile[i] = f2bf(src[i]);          // coalesced read, linear LDS write
  }
  __syncthreads();
#pragma unroll 7
  for (int j = 0; j < 49; ++j) {
    int o = j * 256 + threadIdx.x;
    int c = o & 255, p = o >> 8;
    dst[o] = tile[c * 49 + p];       // strided LDS read (conflict-light), coalesced store
  }
}

// W7 -> bf16 [2048][1024] (xc rows then xr rows)
__global__ void pack_w7(const float* __restrict__ W7c, const float* __restrict__ W7r,
                        ushort* __restrict__ W7p) {
  int idx = blockIdx.x * 256 + threadIdx.x;  // exactly 2048*1024
  float v = (idx < 1048576) ? W7c[idx] : W7r[idx - 1048576];
  W7p[idx] = f2bf(v);
}

// ---------------- conv GEMM (split-bf16, 3-term) + fused repack epilogues -------
// Q variant: n<128 -> fuse qv half (token-major [b][p][c]); n>=128 -> qk hi/lo rows
__global__ __launch_bounds__(256) void gemm_conv_q(
    const ushort* __restrict__ Ah, const ushort* __restrict__ Al,
    const ushort* __restrict__ Bh, const ushort* __restrict__ Bl,
    const float* __restrict__ bias, ushort* __restrict__ fuse,
    ushort* __restrict__ qk_h, ushort* __restrict__ qk_l) {
  const int lane = threadIdx.x & 63, wv = threadIdx.x >> 6;
  const int r = lane & 15, g = lane >> 4;
  const int row0 = blockIdx.x * 64 + wv * 16;
  const ushort* arh = Ah + (size_t)(row0 + r) * 256 + g * 8;
  const ushort* arl = Al + (size_t)(row0 + r) * 256 + g * 8;
  f32x4 acc[16];
#pragma unroll
  for (int i = 0; i < 16; ++i) acc[i] = f32x4{0.f, 0.f, 0.f, 0.f};
#pragma unroll
  for (int kc = 0; kc < 8; ++kc) {
    short8 ah = *(const short8*)(arh + kc * 32);
    short8 al = *(const short8*)(arl + kc * 32);
    const ushort* bbh = Bh + r * 256 + kc * 32 + g * 8;
    const ushort* bbl = Bl + r * 256 + kc * 32 + g * 8;
#pragma unroll
    for (int nt = 0; nt < 16; ++nt) {
      short8 bh = *(const short8*)(bbh + nt * 16 * 256);
      short8 bl = *(const short8*)(bbl + nt * 16 * 256);
      acc[nt] = mfma16(ah, bh, acc[nt]);
      acc[nt] = mfma16(al, bh, acc[nt]);
      acc[nt] = mfma16(ah, bl, acc[nt]);
    }
  }
  const int qr = row0 + g * 4;
#pragma unroll
  for (int nt = 0; nt < 16; ++nt) {
    int n = nt * 16 + r;
    float bs = bias[n];
#pragma unroll
    for (int e = 0; e < 4; ++e) {
      float v = acc[nt][e] + bs;
      int q = qr + e;
      if (n < 128) {
        int b = q / 49, p = q - b * 49;
        fuse[(size_t)b * IN_ + p * 256 + n] = f2bf(v);
      } else {
        size_t j = (size_t)q * 128 + (n - 128);
        ushort h = f2bf(v);
        qk_h[j] = h; qk_l[j] = f2bf(v - bf2f(h));
      }
    }
  }
}

// S variant: n<128 -> svT [128][3136]; n>=128 -> sk hi/lo rows
__global__ __launch_bounds__(256) void gemm_conv_s(
    const ushort* __restrict__ Ah, const ushort* __restrict__ Al,
    const ushort* __restrict__ Bh, const ushort* __restrict__ Bl,
    const float* __restrict__ bias, ushort* __restrict__ svT,
    ushort* __restrict__ sk_h, ushort* __restrict__ sk_l) {
  const int lane = threadIdx.x & 63, wv = threadIdx.x >> 6;
  const int r = lane & 15, g = lane >> 4;
  const int row0 = blockIdx.x * 64 + wv * 16;
  const ushort* arh = Ah + (size_t)(row0 + r) * 256 + g * 8;
  const ushort* arl = Al + (size_t)(row0 + r) * 256 + g * 8;
  f32x4 acc[16];
#pragma unroll
  for (int i = 0; i < 16; ++i) acc[i] = f32x4{0.f, 0.f, 0.f, 0.f};
#pragma unroll
  for (int kc = 0; kc < 8; ++kc) {
    short8 ah = *(const short8*)(arh + kc * 32);
    short8 al = *(const short8*)(arl + kc * 32);
    const ushort* bbh = Bh + r * 256 + kc * 32 + g * 8;
    const ushort* bbl = Bl + r * 256 + kc * 32 + g * 8;
#pragma unroll
    for (int nt = 0; nt < 16; ++nt) {
      short8 bh = *(const short8*)(bbh + nt * 16 * 256);
      short8 bl = *(const short8*)(bbl + nt * 16 * 256);
      acc[nt] = mfma16(ah, bh, acc[nt]);
      acc[nt] = mfma16(al, bh, acc[nt]);
      acc[nt] = mfma16(ah, bl, acc[nt]);
    }
  }
  const int qr = row0 + g * 4;
#pragma unroll
  for (int nt = 0; nt < 16; ++nt) {
    int n = nt * 16 + r;
    float bs = bias[n];
#pragma unroll
    for (int e = 0; e < 4; ++e) {
      float v = acc[nt][e] + bs;
      int k = qr + e;
      if (n < 128) {
        svT[(size_t)n * M_S + k] = f2bf(v);
      } else {
        size_t j = (size_t)k * 128 + (n - 128);
        ushort h = f2bf(v);
        sk_h[j] = h; sk_l[j] = f2bf(v - bf2f(h));
      }
    }
  }
}

// ---------------- fused attention: 4-wave blocks, LDS K/V, reg double-buffer ----
// block = 256 thr = 4 waves; 128 q-rows/block (32/wave); key chunk z of NZ.
// Pipeline per tile: [bar] publish regs->LDS ; issue loads(t+1) ; [bar] compute(t)
__global__ __launch_bounds__(256) void attn_kernel(
    const ushort* __restrict__ Qh, const ushort* __restrict__ Ql,
    const ushort* __restrict__ Kh, const ushort* __restrict__ Kl,
    const ushort* __restrict__ Vt, float* __restrict__ pnum,
    float* __restrict__ pden) {
  __shared__ ushort khs[32 * 128];
  __shared__ ushort kls[32 * 128];
  __shared__ ushort vvs[128 * 32];
  __shared__ ushort plds[4 * 2 * 16 * PSTR];
  const int tid = threadIdx.x;
  const int w = tid >> 6, lane = tid & 63;
  const int r = lane & 15, g = lane >> 4;
  const int q0 = blockIdx.x * 128 + w * 32;
  const int z = blockIdx.y;
  const int t0 = z * 24 + (z < 2 ? z : 2);
  const int tn = 24 + (z < 2 ? 1 : 0);
  ushort* pw = plds + w * (2 * 16 * PSTR);

  // per-thread staging geometry (constant)
  const int row0s = tid >> 4, c8s = tid & 15;          // K chunk (i adds 16 rows)
  const int cvs = tid >> 2, kc2s = tid & 3;            // V chunk (i adds 64 c)
  const int kloff0 = row0s * 128 + ((c8s ^ (row0s & 7)) << 3);
  const int kloff1 = (row0s + 16) * 128 + ((c8s ^ ((row0s + 16) & 7)) << 3);

  short8 aqh[2][4], aql[2][4];
#pragma unroll
  for (int mt = 0; mt < 2; ++mt)
#pragma unroll
    for (int kc = 0; kc < 4; ++kc) {
      const int rowq = q0 + mt * 16 + r;
      aqh[mt][kc] = *(const short8*)(Qh + (size_t)rowq * 128 + kc * 32 + g * 8);
      aql[mt][kc] = *(const short8*)(Ql + (size_t)rowq * 128 + kc * 32 + g * 8);
    }

  f32x4 acc[2][8];
#pragma unroll
  for (int mt = 0; mt < 2; ++mt)
#pragma unroll
    for (int ct = 0; ct < 8; ++ct) acc[mt][ct] = f32x4{0.f, 0.f, 0.f, 0.f};
  float den[2][4];
#pragma unroll
  for (int mt = 0; mt < 2; ++mt)
#pragma unroll
    for (int e = 0; e < 4; ++e) den[mt][e] = 0.f;

  // prefetch registers (double-buffer staging through regs)
  short8 pkh0, pkh1, pkl0, pkl1, pv0, pv1;
  {
    const int kb = t0 * 32;
    pkh0 = *(const short8*)(Kh + (size_t)(kb + row0s) * 128 + c8s * 8);
    pkh1 = *(const short8*)(Kh + (size_t)(kb + row0s + 16) * 128 + c8s * 8);
    pkl0 = *(const short8*)(Kl + (size_t)(kb + row0s) * 128 + c8s * 8);
    pkl1 = *(const short8*)(Kl + (size_t)(kb + row0s + 16) * 128 + c8s * 8);
    pv0  = *(const short8*)(Vt + (size_t)cvs * M_S + kb + kc2s * 8);
    pv1  = *(const short8*)(Vt + (size_t)(cvs + 64) * M_S + kb + kc2s * 8);
  }

  for (int t = t0; t < t0 + tn; ++t) {
    __syncthreads();  // readers of previous tile done
    // publish prefetched tile to LDS
    *(short8*)(khs + kloff0) = pkh0;
    *(short8*)(khs + kloff1) = pkh1;
    *(short8*)(kls + kloff0) = pkl0;
    *(short8*)(kls + kloff1) = pkl1;
    *(short8*)(vvs + cvs * 32 + kc2s * 8) = pv0;
    *(short8*)(vvs + (cvs + 64) * 32 + kc2s * 8) = pv1;
    // issue next tile's loads (overlap with this tile's compute)
    if (t + 1 < t0 + tn) {
      const int kb = (t + 1) * 32;
      pkh0 = *(const short8*)(Kh + (size_t)(kb + row0s) * 128 + c8s * 8);
      pkh1 = *(const short8*)(Kh + (size_t)(kb + row0s + 16) * 128 + c8s * 8);
      pkl0 = *(const short8*)(Kl + (size_t)(kb + row0s) * 128 + c8s * 8);
      pkl1 = *(const short8*)(Kl + (size_t)(kb + row0s + 16) * 128 + c8s * 8);
      pv0  = *(const short8*)(Vt + (size_t)cvs * M_S + kb + kc2s * 8);
      pv1  = *(const short8*)(Vt + (size_t)(cvs + 64) * M_S + kb + kc2s * 8);
    }
    __syncthreads();  // tile t visible to all waves

    // ---- QK^T from LDS (3-term split-bf16) ----
    f32x4 lg[2][2];
#pragma unroll
    for (int kt = 0; kt < 2; ++kt) {
      const int rowk = kt * 16 + r;
      const int kbase = rowk * 128;
      short8 bh[4], bl[4];
#pragma unroll
      for (int kc = 0; kc < 4; ++kc) {
        const int pos = kbase + (((kc * 4 + g) ^ (rowk & 7)) << 3);
        bh[kc] = *(const short8*)(khs + pos);
        bl[kc] = *(const short8*)(kls + pos);
      }
#pragma unroll
      for (int mt = 0; mt < 2; ++mt) {
        f32x4 c = f32x4{0.f, 0.f, 0.f, 0.f};
#pragma unroll
        for (int kc = 0; kc < 4; ++kc) {
          c = mfma16(aqh[mt][kc], bh[kc], c);
          c = mfma16(aql[mt][kc], bh[kc], c);
          c = mfma16(aqh[mt][kc], bl[kc], c);
        }
        lg[mt][kt] = c;
      }
    }
    // ---- exp, den partials, stash P (per-wave LDS slice, padded stride) ----
#pragma unroll
    for (int mt = 0; mt < 2; ++mt)
#pragma unroll
      for (int kt = 0; kt < 2; ++kt)
#pragma unroll
        for (int e = 0; e < 4; ++e) {
          float p = __expf(lg[mt][kt][e] - SHIFTC);
          den[mt][e] += p;
          pw[mt * 16 * PSTR + (g * 4 + e) * PSTR + kt * 16 + r] = f2bf(p);
        }
    // ---- PV from LDS; V fragments hoisted (mt-invariant) ----
    short8 vf[8];
#pragma unroll
    for (int ct = 0; ct < 8; ++ct)
      vf[ct] = *(const short8*)(vvs + (ct * 16 + r) * 32 + g * 8);
#pragma unroll
    for (int mt = 0; mt < 2; ++mt) {
      short8 pf = *(const short8*)(pw + mt * 16 * PSTR + r * PSTR + g * 8);
#pragma unroll
      for (int ct = 0; ct < 8; ++ct)
        acc[mt][ct] = mfma16(pf, vf[ct], acc[mt][ct]);
    }
  }

#pragma unroll
  for (int mt = 0; mt < 2; ++mt)
#pragma unroll
    for (int e = 0; e < 4; ++e) {
      float d = den[mt][e];
      d += __shfl_xor(d, 1);
      d += __shfl_xor(d, 2);
      d += __shfl_xor(d, 4);
      d += __shfl_xor(d, 8);
      den[mt][e] = d;
    }
#pragma unroll
  for (int mt = 0; mt < 2; ++mt)
#pragma unroll
    for (int ct = 0; ct < 8; ++ct)
#pragma unroll
      for (int e = 0; e < 4; ++e) {
        int q = q0 + mt * 16 + g * 4 + e;
        int c = ct * 16 + r;
        pnum[((size_t)z * M_Q + q) * 128 + c] = acc[mt][ct][e];
      }
  if (r == 0) {
#pragma unroll
    for (int mt = 0; mt < 2; ++mt)
#pragma unroll
      for (int e = 0; e < 4; ++e)
        pden[(size_t)z * M_Q + q0 + mt * 16 + g * 4 + e] = den[mt][e];
  }
}

// combine key-split partials -> att half of fuse (token-major, coalesced)
typedef ushort ushort4v __attribute__((ext_vector_type(4)));
__global__ void attn_reduce(const float* __restrict__ pnum, const float* __restrict__ pden,
                            ushort* __restrict__ fuse) {
  int idx = blockIdx.x * 256 + threadIdx.x;  // exactly 25088*32 (c-quads)
  int q = idx >> 5;
  int c4 = (idx & 31) * 4;
  float4 s = {0.f, 0.f, 0.f, 0.f};
  float d = 0.f;
#pragma unroll
  for (int z = 0; z < NZ; ++z) {
    float4 v = *(const float4*)(pnum + ((size_t)z * M_Q + q) * 128 + c4);
    s.x += v.x; s.y += v.y; s.z += v.z; s.w += v.w;
    d += pden[(size_t)z * M_Q + q];
  }
  float inv = 1.0f / d;
  int b = q / 49, p = q - b * 49;
  ushort4v o;
  o[0] = f2bf(s.x * inv); o[1] = f2bf(s.y * inv);
  o[2] = f2bf(s.z * inv); o[3] = f2bf(s.w * inv);
  *(ushort4v*)(fuse + (size_t)b * IN_ + p * 256 + 128 + c4) = o;
}

// ---------------- fc6: [512][12544] x W6p[2048][12544]^T bf16, K-split FZ=8 -----
__global__ __launch_bounds__(256) void fc6_kernel(
    const ushort* __restrict__ fuse, const ushort* __restrict__ W6p,
    float* __restrict__ part) {
  const int lane = threadIdx.x & 63, wv = threadIdx.x >> 6;
  const int r = lane & 15, g = lane >> 4;
  const int m0 = wv * 128;
  const int n0 = blockIdx.x * 64;
  const int kz = blockIdx.y;
  const int k0 = kz * 1568;
  f32x4 acc[8][4];
#pragma unroll
  for (int mt = 0; mt < 8; ++mt)
#pragma unroll
    for (int nt = 0; nt < 4; ++nt) acc[mt][nt] = f32x4{0.f, 0.f, 0.f, 0.f};
  const ushort* wrow[4];
#pragma unroll
  for (int nt = 0; nt < 4; ++nt)
    wrow[nt] = W6p + (size_t)(n0 + nt * 16 + r) * IN_;
  for (int kk = 0; kk < 1568; kk += 32) {
    const int kcol = k0 + kk + g * 8;
    short8 af[8];
#pragma unroll
    for (int mt = 0; mt < 8; ++mt)
      af[mt] = *(const short8*)(fuse + (size_t)(m0 + mt * 16 + r) * IN_ + kcol);
    short8 bfr[4];
#pragma unroll
    for (int nt = 0; nt < 4; ++nt) bfr[nt] = *(const short8*)(wrow[nt] + kcol);
#pragma unroll
    for (int mt = 0; mt < 8; ++mt)
#pragma unroll
      for (int nt = 0; nt < 4; ++nt) acc[mt][nt] = mfma16(af[mt], bfr[nt], acc[mt][nt]);
  }
#pragma unroll
  for (int mt = 0; mt < 8; ++mt)
#pragma unroll
    for (int nt = 0; nt < 4; ++nt)
#pragma unroll
      for (int e = 0; e < 4; ++e) {
        int m = m0 + mt * 16 + g * 4 + e;
        int n = n0 + nt * 16 + r;
        part[(size_t)kz * 1048576 + (size_t)m * 2048 + n] = acc[mt][nt][e];
      }
}

// sum split-K partials + bias + relu -> X7 bf16 [512][2048]
__global__ void fc6_reduce(const float* __restrict__ part, const float* __restrict__ b6c,
                           const float* __restrict__ b6r, ushort* __restrict__ X7) {
  int idx = blockIdx.x * 256 + threadIdx.x;  // exactly 512*2048
  int n = idx & 2047;
  float s = 0.f;
#pragma unroll
  for (int z = 0; z < FZ; ++z) s += part[(size_t)z * 1048576 + idx];
  s += (n < 1024) ? b6c[n] : b6r[n - 1024];
  s = fmaxf(s, 0.f);
  X7[idx] = f2bf(s);
}

// ---------------- fc7: [512][1024] x W7p[2048][1024]^T bf16 per half ------------
__global__ __launch_bounds__(256) void fc7_kernel(
    const ushort* __restrict__ X7, const ushort* __restrict__ W7p,
    const float* __restrict__ b7c, const float* __restrict__ b7r,
    float* __restrict__ out) {
  const int lane = threadIdx.x & 63, wv = threadIdx.x >> 6;
  const int r = lane & 15, g = lane >> 4;
  const int m0 = blockIdx.x * 64 + wv * 16;
  const int n0 = blockIdx.y * 64;
  const int half = (n0 >= 1024) ? 1 : 0;
  const int nn0 = n0 - half * 1024;
  const float* b7 = half ? b7r : b7c;
  f32x4 acc[4];
#pragma unroll
  for (int nt = 0; nt < 4; ++nt) acc[nt] = f32x4{0.f, 0.f, 0.f, 0.f};
  const ushort* arow = X7 + (size_t)(m0 + r) * 2048 + half * 1024;
  for (int kk = 0; kk < 1024; kk += 32) {
    short8 a = *(const short8*)(arow + kk + g * 8);
#pragma unroll
    for (int nt = 0; nt < 4; ++nt) {
      short8 bb = *(const short8*)(W7p + (size_t)(half * 1024 + nn0 + nt * 16 + r) * 1024 + kk + g * 8);
      acc[nt] = mfma16(a, bb, acc[nt]);
    }
  }
  float* obase = out + (size_t)half * 524288;
#pragma unroll
  for (int nt = 0; nt < 4; ++nt) {
#pragma unroll
    for (int e = 0; e < 4; ++e) {
      int m = m0 + g * 4 + e;
      int n = nn0 + nt * 16 + r;
      obase[(size_t)m * 1024 + n] = fmaxf(acc[nt][e] + b7[n], 0.f);
    }
  }
}

// ---------------- launch ----------------
extern "C" void kernel_launch(void* const* d_in, const int* in_sizes, int n_in,
                              void* d_out, int out_size, void* d_ws, size_t ws_size,
                              hipStream_t stream) {
  const float* x    = (const float*)d_in[0];
  const float* sup  = (const float*)d_in[1];
  const float* Wqv  = (const float*)d_in[2];
  const float* bqv  = (const float*)d_in[3];
  const float* Wqk  = (const float*)d_in[4];
  const float* bqk  = (const float*)d_in[5];
  const float* Wsv  = (const float*)d_in[6];
  const float* bsv  = (const float*)d_in[7];
  const float* Wsk  = (const float*)d_in[8];
  const float* bsk  = (const float*)d_in[9];
  const float* W6c  = (const float*)d_in[10];
  const float* b6c  = (const float*)d_in[11];
  const float* W7c  = (const float*)d_in[12];
  const float* b7c  = (const float*)d_in[13];
  const float* W6r  = (const float*)d_in[14];
  const float* b6r  = (const float*)d_in[15];
  const float* W7r  = (const float*)d_in[16];
  const float* b7r  = (const float*)d_in[17];
  float* out = (float*)d_out;

  char* base = (char*)d_ws;
  size_t off = 0;
  auto alloc = [&](size_t bytes) {
    char* p = base + off;
    off += (bytes + 255) & ~(size_t)255;
    return p;
  };
  // Region A: stage 1 = Xp/Xs hi/lo (28.9MB); stage 2 (after convs) = W6p+W7p (55.6MB)
  char* regionA = alloc((size_t)2048 * IN_ * 2 + (size_t)2048 * 1024 * 2);
  ushort* Xp_h = (ushort*)(regionA);
  ushort* Xp_l = (ushort*)(regionA + 12845056);
  ushort* Xs_h = (ushort*)(regionA + 25690112);
  ushort* Xs_l = (ushort*)(regionA + 27295744);
  ushort* W6p  = (ushort*)(regionA);
  ushort* W7p  = (ushort*)(regionA + (size_t)2048 * IN_ * 2);
  // Region B: attn pnum (51.4MB) then fc6 part (33.6MB)
  char* regionB = alloc((size_t)NZ * M_Q * 128 * 4);
  float* pnum = (float*)regionB;
  float* part = (float*)regionB;
  // Persistent region
  ushort* Wq_h = (ushort*)alloc(65536 * 2);
  ushort* Wq_l = (ushort*)alloc(65536 * 2);
  ushort* Ws_h = (ushort*)alloc(65536 * 2);
  ushort* Ws_l = (ushort*)alloc(65536 * 2);
  float*  biasq = (float*)alloc(256 * 4);
  float*  biass = (float*)alloc(256 * 4);
  ushort* fuse = (ushort*)alloc((size_t)512 * IN_ * 2);
  ushort* qk_h = (ushort*)alloc((size_t)M_Q * 128 * 2);
  ushort* qk_l = (ushort*)alloc((size_t)M_Q * 128 * 2);
  ushort* sk_h = (ushort*)alloc((size_t)M_S * 128 * 2);
  ushort* sk_l = (ushort*)alloc((size_t)M_S * 128 * 2);
  ushort* svT  = (ushort*)alloc((size_t)M_S * 128 * 2);
  float*  pden = (float*)alloc((size_t)NZ * M_Q * 4);
  ushort* X7   = (ushort*)alloc((size_t)512 * 2048 * 2);
  if (off > ws_size) return;  // insufficient scratch; validation will show poison

  // 1) coalesced transpose+pack to bf16 hi/lo, token-major
  transpose_pack<<<dim3(512, 1), dim3(256), 0, stream>>>(x, Xp_h, Xp_l, 49);
  transpose_pack<<<dim3(16, 4), dim3(256), 0, stream>>>(sup, Xs_h, Xs_l, 196);
  pack_w<<<dim3(515), dim3(256), 0, stream>>>(Wqv, Wqk, bqv, bqk, Wsv, Wsk, bsv, bsk,
                                              Wq_h, Wq_l, biasq, Ws_h, Ws_l, biass);
  // 2) 1x1 convs with fused repack epilogues
  gemm_conv_q<<<dim3(392), dim3(256), 0, stream>>>(Xp_h, Xp_l, Wq_h, Wq_l, biasq,
                                                   fuse, qk_h, qk_l);
  gemm_conv_s<<<dim3(49), dim3(256), 0, stream>>>(Xs_h, Xs_l, Ws_h, Ws_l, biass,
                                                  svT, sk_h, sk_l);
  // 3) pack MLP weights to bf16 into regionA (Xp/Xs now dead)
  pack_w6<<<dim3(2048), dim3(256), 0, stream>>>(W6c, W6r, W6p);
  pack_w7<<<dim3(8192), dim3(256), 0, stream>>>(W7c, W7r, W7p);
  // 4) fused attention (4-wave LDS-staged, reg-prefetch dbuf, key-split) + combine
  attn_kernel<<<dim3(196, NZ), dim3(256), 0, stream>>>(qk_h, qk_l, sk_h, sk_l, svT,
                                                       pnum, pden);
  attn_reduce<<<dim3(3136), dim3(256), 0, stream>>>(pnum, pden, fuse);
  // 5) fc6 (K-split deterministic) + reduce+relu
  fc6_kernel<<<dim3(32, FZ), dim3(256), 0, stream>>>(fuse, W6p, part);
  fc6_reduce<<<dim3(4096), dim3(256), 0, stream>>>(part, b6c, b6r, X7);
  // 6) fc7 + bias + relu -> d_out (xc then xr)
  fc7_kernel<<<dim3(8, 32), dim3(256), 0, stream>>>(X7, W7p, b7c, b7r, out);
}